// Round 10
// baseline (654.408 us; speedup 1.0000x reference)
//
#include <hip/hip_runtime.h>
#include <hip/hip_bf16.h>

typedef unsigned short u16;
typedef float f32x4 __attribute__((ext_vector_type(4)));
typedef u16   u16x8 __attribute__((ext_vector_type(8)));
typedef u16   u16x4 __attribute__((ext_vector_type(4)));
typedef short s16x8 __attribute__((ext_vector_type(8)));

__device__ __forceinline__ u16 f2bf(float f) {
  unsigned u = __builtin_bit_cast(unsigned, f);
  unsigned r = (u + 0x7fffu + ((u >> 16) & 1u)) >> 16;
  return (u16)r;
}
__device__ __forceinline__ u16 cvtbf(float f) {
  return __builtin_bit_cast(u16, __float2bfloat16(f));
}

#define GL_LDS16(gp, lp)                                                     \
  __builtin_amdgcn_global_load_lds((const __attribute__((address_space(1))) void*)(gp), \
                                   (__attribute__((address_space(3))) void*)(lp), 16, 0, 0)

// ---- inter-block sync helpers (device scope; all users' grids are fully co-resident) ----
__device__ __forceinline__ void spin_ge(unsigned* f, unsigned v) {
  if (threadIdx.x == 0)
    while (__hip_atomic_load(f, __ATOMIC_ACQUIRE, __HIP_MEMORY_SCOPE_AGENT) < v)
      __builtin_amdgcn_s_sleep(8);
  __syncthreads();
}
__device__ __forceinline__ void release_add(unsigned* f) {
  __syncthreads();   // all waves drained (stores retired to L2) before release
  if (threadIdx.x == 0)
    __hip_atomic_fetch_add(f, 1u, __ATOMIC_RELEASE, __HIP_MEMORY_SCOPE_AGENT);
}
// flag layout (unsigned words): F0[8]@0, FU1[16]@16, C1[4]@32, FU2[32]@40, C2[2]@72, FU3[64]@80, CY[16]@144

// ===== K1: B=A*A^T (136 sym tiles, mirrored) + rd2 + diag 64-inverses -> M + flag zero + Xbf =====
__global__ __launch_bounds__(256) void k_bbtx(const float* __restrict__ A, float* __restrict__ B,
                                              float* __restrict__ rd2, float* __restrict__ M,
                                              unsigned* __restrict__ FL,
                                              const float* __restrict__ X, u16* __restrict__ Xbf) {
  const int bid = blockIdx.x;
  const int tid = threadIdx.x;
  if (bid >= 136) {
    // X fp32 -> bf16 in A-fragment order: [mi256][half(32)][msub(16)][lane(64)][8]
    for (int gid = (bid - 136) * 256 + tid; gid < (1 << 23); gid += 2048 * 256) {
      const int mi   = gid >> 15;
      const int half = (gid >> 10) & 31;
      const int msub = (gid >> 6) & 15;
      const int lane = gid & 63;
      const int m = mi * 256 + msub * 16 + (lane & 15);
      const int k = half * 32 + (lane >> 4) * 8;
      const float* s = X + (size_t)m * 1024 + k;
      f32x4 u = *(const f32x4*)s;
      f32x4 v = *(const f32x4*)(s + 4);
      u16x8 h;
      h[0] = cvtbf(u[0]); h[1] = cvtbf(u[1]); h[2] = cvtbf(u[2]); h[3] = cvtbf(u[3]);
      h[4] = cvtbf(v[0]); h[5] = cvtbf(v[1]); h[6] = cvtbf(v[2]); h[7] = cvtbf(v[3]);
      *(u16x8*)(Xbf + (size_t)gid * 8) = h;
    }
    return;
  }
  __shared__ float s0[32][68];
  __shared__ float s1[32][68];
  __shared__ float Ct[64][68];
  __shared__ float rdl[64];
  if (bid == 0 && tid < 256) FL[tid] = 0;   // zero all sync flags (consumed by k_minv/k_yw)

  int t = bid, ii = 0;
  while (t >= 16 - ii) { t -= 16 - ii; ++ii; }
  const int jj = ii + t;
  const int i0 = ii * 64, j0 = jj * 64;
  const int tx = tid & 15, ty = tid >> 4;
  const int sr = tid >> 2, sc = (tid & 3) * 8;
  f32x4 acc[4];
#pragma unroll
  for (int q = 0; q < 4; ++q) acc[q] = {0.f, 0.f, 0.f, 0.f};

  for (int k0 = 0; k0 < 1024; k0 += 32) {
    f32x4 a0 = *(const f32x4*)&A[(size_t)(i0 + sr) * 1024 + k0 + sc];
    f32x4 a1 = *(const f32x4*)&A[(size_t)(i0 + sr) * 1024 + k0 + sc + 4];
    f32x4 b0 = *(const f32x4*)&A[(size_t)(j0 + sr) * 1024 + k0 + sc];
    f32x4 b1 = *(const f32x4*)&A[(size_t)(j0 + sr) * 1024 + k0 + sc + 4];
    __syncthreads();
#pragma unroll
    for (int q = 0; q < 4; ++q) {
      s0[sc + q][sr] = a0[q]; s0[sc + 4 + q][sr] = a1[q];
      s1[sc + q][sr] = b0[q]; s1[sc + 4 + q][sr] = b1[q];
    }
    __syncthreads();
#pragma unroll
    for (int kk = 0; kk < 32; ++kk) {
      f32x4 av = *(const f32x4*)&s0[kk][ty * 4];
      f32x4 bv = *(const f32x4*)&s1[kk][tx * 4];
#pragma unroll
      for (int q = 0; q < 4; ++q) acc[q] += bv * av[q];
    }
  }
#pragma unroll
  for (int q = 0; q < 4; ++q)
    *(f32x4*)&B[(size_t)(i0 + ty * 4 + q) * 1024 + j0 + tx * 4] = acc[q];

  if (ii != jj) {
#pragma unroll
    for (int q = 0; q < 4; ++q)
#pragma unroll
      for (int w = 0; w < 4; ++w)
        B[(size_t)(j0 + tx * 4 + w) * 1024 + i0 + ty * 4 + q] = acc[q][w];
    return;
  }
  // diagonal block: rd2 + 64x64 inverse T = (I+L)^-1 -> M diag (exact k_tinv semantics)
  if (tx == ty) {
#pragma unroll
    for (int q = 0; q < 4; ++q) {
      float v = 2.0f / acc[q][q];
      rdl[ty * 4 + q] = v;
      rd2[i0 + ty * 4 + q] = v;
    }
  }
  __syncthreads();
#pragma unroll
  for (int q = 0; q < 4; ++q)
#pragma unroll
    for (int j = 0; j < 4; ++j) {
      int r = ty * 4 + q, c = tx * 4 + j;
      Ct[r][c] = (c > r) ? acc[q][j] * rdl[c] : 0.0f;
    }
  __syncthreads();
  if (tid < 64) {
    float pc[64];
#pragma unroll
    for (int r = 0; r < 64; ++r) pc[r] = (r == tid) ? 1.0f : 0.0f;
#pragma unroll
    for (int i = 0; i < 63; ++i) {
      const float pi = pc[i];
#pragma unroll
      for (int j = i + 1; j < 64; ++j) pc[j] -= Ct[i][j] * pi;
    }
#pragma unroll
    for (int r = 0; r < 64; ++r) M[(size_t)(i0 + r) * 1024 + i0 + tid] = pc[r];
  }
}

// ---- shared GEMM-tile bodies for the M chain (U stored in M's upper triangle, ld=1024) ----
__device__ __forceinline__ void u_tile(const float* __restrict__ B, const float* __restrict__ rd2,
                                       const float* __restrict__ M, float* __restrict__ ub,
                                       int a, int s, int ti, int tj,
                                       float (*sA)[68], float (*sB)[68]) {
  const int tid = threadIdx.x;
  const int m0 = a + s + ti * 64, n0 = a + tj * 64;
  const int tx = tid & 15, ty = tid >> 4;
  const int asr = tid >> 2, asc = (tid & 3) * 8;
  const int bkr = tid >> 3, bnc = (tid & 7) * 8;
  const float r2 = rd2[m0 + asr];
  f32x4 acc[4];
#pragma unroll
  for (int q = 0; q < 4; ++q) acc[q] = {0.f, 0.f, 0.f, 0.f};
  for (int k0 = tj * 64; k0 < s; k0 += 32) {
    f32x4 a0 = *(const f32x4*)&B[(size_t)(m0 + asr) * 1024 + a + k0 + asc];
    f32x4 a1 = *(const f32x4*)&B[(size_t)(m0 + asr) * 1024 + a + k0 + asc + 4];
    f32x4 b0 = *(const f32x4*)&M[(size_t)(a + k0 + bkr) * 1024 + n0 + bnc];
    f32x4 b1 = *(const f32x4*)&M[(size_t)(a + k0 + bkr) * 1024 + n0 + bnc + 4];
    a0 *= r2; a1 *= r2;
    __syncthreads();
#pragma unroll
    for (int q = 0; q < 4; ++q) { sA[asc + q][asr] = a0[q]; sA[asc + 4 + q][asr] = a1[q]; }
    *(f32x4*)&sB[bkr][bnc] = b0;
    *(f32x4*)&sB[bkr][bnc + 4] = b1;
    __syncthreads();
#pragma unroll
    for (int kk = 0; kk < 32; ++kk) {
      f32x4 av = *(const f32x4*)&sA[kk][ty * 4];
      f32x4 bv = *(const f32x4*)&sB[kk][tx * 4];
#pragma unroll
      for (int q = 0; q < 4; ++q) acc[q] += bv * av[q];
    }
  }
#pragma unroll
  for (int q = 0; q < 4; ++q)
    *(f32x4*)&ub[(size_t)(ti * 64 + ty * 4 + q) * 1024 + tj * 64 + tx * 4] = acc[q];
}

__device__ __forceinline__ void moff_tile(float* __restrict__ M, const float* __restrict__ ub,
                                          int a, int s, int ti, int tj,
                                          float (*sA)[68], float (*sB)[68]) {
  const int tid = threadIdx.x;
  const int m0 = a + s + ti * 64, n0 = a + tj * 64;
  const int tx = tid & 15, ty = tid >> 4;
  const int asr = tid >> 2, asc = (tid & 3) * 8;
  const int bkr = tid >> 3, bnc = (tid & 7) * 8;
  const int kmax = (ti + 1) * 64;
  f32x4 acc[4];
#pragma unroll
  for (int q = 0; q < 4; ++q) acc[q] = {0.f, 0.f, 0.f, 0.f};
  for (int k0 = 0; k0 < kmax; k0 += 32) {
    f32x4 a0 = *(const f32x4*)&M[(size_t)(m0 + asr) * 1024 + a + s + k0 + asc];
    f32x4 a1 = *(const f32x4*)&M[(size_t)(m0 + asr) * 1024 + a + s + k0 + asc + 4];
    f32x4 b0 = *(const f32x4*)&ub[(size_t)(k0 + bkr) * 1024 + tj * 64 + bnc];
    f32x4 b1 = *(const f32x4*)&ub[(size_t)(k0 + bkr) * 1024 + tj * 64 + bnc + 4];
    __syncthreads();
#pragma unroll
    for (int q = 0; q < 4; ++q) { sA[asc + q][asr] = a0[q]; sA[asc + 4 + q][asr] = a1[q]; }
    *(f32x4*)&sB[bkr][bnc] = b0;
    *(f32x4*)&sB[bkr][bnc + 4] = b1;
    __syncthreads();
#pragma unroll
    for (int kk = 0; kk < 32; ++kk) {
      f32x4 av = *(const f32x4*)&sA[kk][ty * 4];
      f32x4 bv = *(const f32x4*)&sB[kk][tx * 4];
#pragma unroll
      for (int q = 0; q < 4; ++q) acc[q] += bv * av[q];
    }
  }
#pragma unroll
  for (int q = 0; q < 4; ++q)
    *(f32x4*)&M[(size_t)(m0 + ty * 4 + q) * 1024 + n0 + tx * 4] = -acc[q];
}

// ===== whole M-inverse chain in ONE dispatch (120 blocks, all co-resident, flag-DAG) =====
__global__ __launch_bounds__(256) void k_minv(const float* __restrict__ B, const float* __restrict__ rd2,
                                              float* __restrict__ M, unsigned* __restrict__ FL) {
  __shared__ float sA[32][68];
  __shared__ float sB[32][68];
  __shared__ float Us[64][68];
  const int bid = blockIdx.x;
  const int tid = threadIdx.x;
  unsigned* F0  = FL;        // [8]
  unsigned* FU1 = FL + 16;   // [16] p*4+ti*2+tj
  unsigned* C1  = FL + 32;   // [4]
  unsigned* FU2 = FL + 40;   // [32] p*16+ti*4+tj
  unsigned* C2  = FL + 72;   // [2]
  unsigned* FU3 = FL + 80;   // [64] ti*8+tj

  if (bid < 8) {
    // ---- level 0 (pair p): U = Cs*M11 (in LDS), M21 = -M22*U ----
    const int p = bid, a = p * 128, m0 = a + 64;
    const int tx = tid & 15, ty = tid >> 4;
    const int asr = tid >> 2, asc = (tid & 3) * 8;
    const int bkr = tid >> 3, bnc = (tid & 7) * 8;
    const float r2 = rd2[m0 + asr];
    f32x4 acc[4];
#pragma unroll
    for (int q = 0; q < 4; ++q) acc[q] = {0.f, 0.f, 0.f, 0.f};
    for (int k0 = 0; k0 < 64; k0 += 32) {
      f32x4 a0 = *(const f32x4*)&B[(size_t)(m0 + asr) * 1024 + a + k0 + asc];
      f32x4 a1 = *(const f32x4*)&B[(size_t)(m0 + asr) * 1024 + a + k0 + asc + 4];
      f32x4 b0 = *(const f32x4*)&M[(size_t)(a + k0 + bkr) * 1024 + a + bnc];
      f32x4 b1 = *(const f32x4*)&M[(size_t)(a + k0 + bkr) * 1024 + a + bnc + 4];
      a0 *= r2; a1 *= r2;
      __syncthreads();
#pragma unroll
      for (int q = 0; q < 4; ++q) { sA[asc + q][asr] = a0[q]; sA[asc + 4 + q][asr] = a1[q]; }
      *(f32x4*)&sB[bkr][bnc] = b0;
      *(f32x4*)&sB[bkr][bnc + 4] = b1;
      __syncthreads();
#pragma unroll
      for (int kk = 0; kk < 32; ++kk) {
        f32x4 av = *(const f32x4*)&sA[kk][ty * 4];
        f32x4 bv = *(const f32x4*)&sB[kk][tx * 4];
#pragma unroll
        for (int q = 0; q < 4; ++q) acc[q] += bv * av[q];
      }
    }
#pragma unroll
    for (int q = 0; q < 4; ++q) *(f32x4*)&Us[ty * 4 + q][tx * 4] = acc[q];
#pragma unroll
    for (int q = 0; q < 4; ++q) acc[q] = {0.f, 0.f, 0.f, 0.f};
    for (int k0 = 0; k0 < 64; k0 += 32) {
      f32x4 a0 = *(const f32x4*)&M[(size_t)(m0 + asr) * 1024 + m0 + k0 + asc];
      f32x4 a1 = *(const f32x4*)&M[(size_t)(m0 + asr) * 1024 + m0 + k0 + asc + 4];
      __syncthreads();
#pragma unroll
      for (int q = 0; q < 4; ++q) { sA[asc + q][asr] = a0[q]; sA[asc + 4 + q][asr] = a1[q]; }
      __syncthreads();
#pragma unroll
      for (int kk = 0; kk < 32; ++kk) {
        f32x4 av = *(const f32x4*)&sA[kk][ty * 4];
        f32x4 bv = *(const f32x4*)&Us[k0 + kk][tx * 4];
#pragma unroll
        for (int q = 0; q < 4; ++q) acc[q] += bv * av[q];
      }
    }
#pragma unroll
    for (int q = 0; q < 4; ++q)
      *(f32x4*)&M[(size_t)(m0 + ty * 4 + q) * 1024 + a + tx * 4] = -acc[q];
    release_add(&F0[p]);
  } else if (bid < 24) {
    // ---- level 1: s=128, pairs 0..3, tiles 2x2 ----
    const int idx = bid - 8;
    const int p = idx >> 2, ti = (idx >> 1) & 1, tj = idx & 1;
    const int a = p * 256;
    float* ub = M + (size_t)(p * 256) * 1024 + p * 256 + 128;
    spin_ge(&F0[2 * p], 1);
    spin_ge(&F0[2 * p + 1], 1);
    u_tile(B, rd2, M, ub, a, 128, ti, tj, sA, sB);
    release_add(&FU1[idx]);
    for (int k = 0; k <= ti; ++k) spin_ge(&FU1[p * 4 + k * 2 + tj], 1);
    moff_tile(M, ub, a, 128, ti, tj, sA, sB);
    release_add(&C1[p]);
  } else if (bid < 56) {
    // ---- level 2: s=256, pairs 0..1, tiles 4x4 ----
    const int idx = bid - 24;
    const int p = idx >> 4, ti = (idx >> 2) & 3, tj = idx & 3;
    const int a = p * 512;
    float* ub = (p == 0) ? (M + 256) : (M + (size_t)512 * 1024 + 768);
    spin_ge(&C1[2 * p], 4);
    spin_ge(&C1[2 * p + 1], 4);
    u_tile(B, rd2, M, ub, a, 256, ti, tj, sA, sB);
    release_add(&FU2[idx]);
    for (int k = 0; k <= ti; ++k) spin_ge(&FU2[p * 16 + k * 4 + tj], 1);
    moff_tile(M, ub, a, 256, ti, tj, sA, sB);
    release_add(&C2[p]);
  } else {
    // ---- level 3: s=512, one pair, tiles 8x8 ----
    const int idx = bid - 56;
    const int ti = idx >> 3, tj = idx & 7;
    float* ub = M + 512;
    spin_ge(&C2[0], 16);
    spin_ge(&C2[1], 16);
    u_tile(B, rd2, M, ub, 0, 512, ti, tj, sA, sB);
    release_add(&FU3[idx]);
    for (int k = 0; k <= ti; ++k) spin_ge(&FU3[k * 8 + tj], 1);
    moff_tile(M, ub, 0, 512, ti, tj, sA, sB);
  }
}

// ===== Y = M*A and Wf = frag(I - At D^-1 Y) fused in one dispatch (512 blocks, flag-gated) =====
__global__ __launch_bounds__(256) void k_yw(const float* __restrict__ M, const float* __restrict__ A,
                                            float* __restrict__ Y, const float* __restrict__ rd2,
                                            u16* __restrict__ Wf, unsigned* __restrict__ FL) {
  __shared__ float sA[32][68];
  __shared__ float sB[32][68];
  const int bid = blockIdx.x;
  const int tid = threadIdx.x;
  unsigned* CY = FL + 144;   // [16] per column-block
  const int tx = tid & 15, ty = tid >> 4;

  if (bid < 256) {
    const int ri = bid >> 4, cj = bid & 15;
    const int m0 = ri * 64, n0 = cj * 64;
    const int kmax = (ri + 1) * 64;
    const int asr = tid >> 2, asc = (tid & 3) * 8;
    const int bkr = tid >> 3, bnc = (tid & 7) * 8;
    f32x4 acc[4];
#pragma unroll
    for (int q = 0; q < 4; ++q) acc[q] = {0.f, 0.f, 0.f, 0.f};
    for (int k0 = 0; k0 < kmax; k0 += 32) {
      f32x4 a0 = *(const f32x4*)&M[(size_t)(m0 + asr) * 1024 + k0 + asc];
      f32x4 a1 = *(const f32x4*)&M[(size_t)(m0 + asr) * 1024 + k0 + asc + 4];
      f32x4 b0 = *(const f32x4*)&A[(size_t)(k0 + bkr) * 1024 + n0 + bnc];
      f32x4 b1 = *(const f32x4*)&A[(size_t)(k0 + bkr) * 1024 + n0 + bnc + 4];
      __syncthreads();
#pragma unroll
      for (int q = 0; q < 4; ++q) { sA[asc + q][asr] = a0[q]; sA[asc + 4 + q][asr] = a1[q]; }
      *(f32x4*)&sB[bkr][bnc] = b0;
      *(f32x4*)&sB[bkr][bnc + 4] = b1;
      __syncthreads();
#pragma unroll
      for (int kk = 0; kk < 32; ++kk) {
        f32x4 av = *(const f32x4*)&sA[kk][ty * 4];
        f32x4 bv = *(const f32x4*)&sB[kk][tx * 4];
#pragma unroll
        for (int q = 0; q < 4; ++q) acc[q] += bv * av[q];
      }
    }
#pragma unroll
    for (int q = 0; q < 4; ++q)
      *(f32x4*)&Y[(size_t)(m0 + ty * 4 + q) * 1024 + n0 + tx * 4] = acc[q];
    release_add(&CY[cj]);
  } else {
    const int kb = ((bid - 256) >> 4) * 64, nb = ((bid - 256) & 15) * 64;
    spin_ge(&CY[(bid - 256) & 15], 16);
    const int sr = tid >> 3, sc = (tid & 7) * 8;
    f32x4 acc[4];
#pragma unroll
    for (int q = 0; q < 4; ++q) acc[q] = {0.f, 0.f, 0.f, 0.f};
    for (int i0 = 0; i0 < 1024; i0 += 32) {
      float r2 = rd2[i0 + sr];
      f32x4 a0 = *(const f32x4*)&A[(size_t)(i0 + sr) * 1024 + kb + sc];
      f32x4 a1 = *(const f32x4*)&A[(size_t)(i0 + sr) * 1024 + kb + sc + 4];
      f32x4 p0 = *(const f32x4*)&Y[(size_t)(i0 + sr) * 1024 + nb + sc];
      f32x4 p1 = *(const f32x4*)&Y[(size_t)(i0 + sr) * 1024 + nb + sc + 4];
      __syncthreads();
      *(f32x4*)&sA[sr][sc]     = a0 * r2;
      *(f32x4*)&sA[sr][sc + 4] = a1 * r2;
      *(f32x4*)&sB[sr][sc]     = p0;
      *(f32x4*)&sB[sr][sc + 4] = p1;
      __syncthreads();
#pragma unroll
      for (int i = 0; i < 32; ++i) {
        f32x4 av = *(const f32x4*)&sA[i][ty * 4];
        f32x4 pv = *(const f32x4*)&sB[i][tx * 4];
#pragma unroll
        for (int q = 0; q < 4; ++q) acc[q] += pv * av[q];
      }
    }
    const int ktile = (kb + ty * 4) >> 5;
    const int kg = ((ty * 4) >> 3) & 3;
    const int e0 = (ty * 4) & 7;
#pragma unroll
    for (int j = 0; j < 4; ++j) {
      int n = nb + tx * 4 + j;
      int nt = n >> 4;
      int ln = kg * 16 + (n & 15);
      u16x4 pk;
#pragma unroll
      for (int q = 0; q < 4; ++q) {
        int kk = kb + ty * 4 + q;
        float w = ((kk == n) ? 1.0f : 0.0f) - acc[q][j];
        pk[q] = f2bf(w);
      }
      *(u16x4*)&Wf[((size_t)(ktile * 64 + nt) * 64 + ln) * 8 + e0] = pk;
    }
  }
}

// ===== 256x256 GEMM, 16 waves (4x4), 64x64/wave, 4 waves/SIMD, counted-vmcnt depth-3 =====
template<int I>
__device__ __forceinline__ void phase_body(const u16* __restrict__ ax, const u16* __restrict__ wbase,
                                           u16* As, u16* Bs, int tid, int wr, int wc, int lane,
                                           f32x4 (&acc)[4][4]) {
  if constexpr (I <= 29)      asm volatile("s_waitcnt vmcnt(4)" ::: "memory");
  else if constexpr (I == 30) asm volatile("s_waitcnt vmcnt(2)" ::: "memory");
  else                        asm volatile("s_waitcnt vmcnt(0)" ::: "memory");
  __builtin_amdgcn_s_barrier();   // UNCONDITIONAL: all waves' half-I loads landed (R9 bug: phase 31 skipped this)
  if constexpr (I + 3 < 32) {   // prefetch half I+3 into slot (I+3)&3 (its last reads ended phase I-1)
    constexpr int j = I + 3, js = j & 3;
    GL_LDS16(ax + (size_t)j * 8192 + tid * 8,     As + js * 8192 + tid * 8);
    GL_LDS16(wbase + (size_t)j * 32768 + tid * 8, Bs + js * 8192 + tid * 8);
  }
  const u16* Asb = As + (I & 3) * 8192;
  const u16* Bsb = Bs + (I & 3) * 8192;
  s16x8 af[4], bf[4];
#pragma unroll
  for (int m = 0; m < 4; ++m) af[m] = *(const s16x8*)&Asb[(wr * 4 + m) * 512 + lane * 8];
#pragma unroll
  for (int n = 0; n < 4; ++n) bf[n] = *(const s16x8*)&Bsb[(wc * 4 + n) * 512 + lane * 8];
  __builtin_amdgcn_s_setprio(1);
#pragma unroll
  for (int m = 0; m < 4; ++m)
#pragma unroll
    for (int n = 0; n < 4; ++n)
      acc[m][n] = __builtin_amdgcn_mfma_f32_16x16x32_bf16(af[m], bf[n], acc[m][n], 0, 0, 0);
  __builtin_amdgcn_s_setprio(0);
}

__global__ __launch_bounds__(1024, 4) void k_out8(const u16* __restrict__ Xbf, const u16* __restrict__ Wf,
                                                  const float* __restrict__ bvec, float* __restrict__ out) {
  __shared__ u16 As[32768];   // 4 slots x 16KB (A half: 256 rows x 32 k bf16)
  __shared__ u16 Bs[32768];   // 4 slots x 16KB (B half)
  const int tid = threadIdx.x;
  const int lane = tid & 63, wid = tid >> 6;
  const int wr = wid >> 2, wc = wid & 3;          // 4M x 4N waves; per-wave out 64x64
  const int lin = blockIdx.x;
  const int xcd = lin & 7, idx = lin >> 3;
  const int mi = xcd * 32 + (idx >> 2);           // XCD-chunked
  const int ni = idx & 3;

  const u16* ax = Xbf + (size_t)mi * 262144;      // per half: 8192 u16 (16KB)
  const u16* wbase = Wf + (size_t)ni * 8192;      // per half: +32768 u16

  f32x4 acc[4][4];
#pragma unroll
  for (int m = 0; m < 4; ++m)
#pragma unroll
    for (int n = 0; n < 4; ++n) acc[m][n] = {0.f, 0.f, 0.f, 0.f};

  // prologue: issue halves 0,1,2 (A+B each, 1 load/thread each)
#pragma unroll
  for (int j = 0; j < 3; ++j) {
    GL_LDS16(ax + (size_t)j * 8192 + tid * 8,     As + j * 8192 + tid * 8);
    GL_LDS16(wbase + (size_t)j * 32768 + tid * 8, Bs + j * 8192 + tid * 8);
  }

#define PH(I) phase_body<I>(ax, wbase, As, Bs, tid, wr, wc, lane, acc);
  PH(0)  PH(1)  PH(2)  PH(3)  PH(4)  PH(5)  PH(6)  PH(7)
  PH(8)  PH(9)  PH(10) PH(11) PH(12) PH(13) PH(14) PH(15)
  PH(16) PH(17) PH(18) PH(19) PH(20) PH(21) PH(22) PH(23)
  PH(24) PH(25) PH(26) PH(27) PH(28) PH(29) PH(30) PH(31)
#undef PH

  const long orow0 = (long)mi * 256 + wr * 64 + (lane >> 4) * 4;
  const int  ocol0 = ni * 256 + wc * 64 + (lane & 15);
#pragma unroll
  for (int aj = 0; aj < 4; ++aj) {
    const int cc = ocol0 + aj * 16;
    const float bb = bvec[cc];
#pragma unroll
    for (int ai = 0; ai < 4; ++ai) {
      const long r = orow0 + ai * 16;
#pragma unroll
      for (int q = 0; q < 4; ++q)
        out[(r + q) * 1024 + cc] = acc[ai][aj][q] + bb;
    }
  }
}

// ===== fallback GEMM (reg-staged A) if workspace too small for Xbf =====
__global__ __launch_bounds__(256) void k_out_r(const float* __restrict__ X, const u16* __restrict__ Wf,
                                               const float* __restrict__ bvec, float* __restrict__ out) {
  __shared__ u16 As[8192];
  __shared__ u16 Bs[8192];
  const int tid = threadIdx.x;
  const int lane = tid & 63, wid = tid >> 6;
  const int wr = wid >> 1, wc = wid & 1;
  const int lin = blockIdx.x;
  const int mi = (lin & 7) * 64 + (lin >> 6);
  const int ni = (lin >> 3) & 7;
  const long m0 = (long)mi * 128;
  const int n0 = ni * 128;

  const float *xs0, *xs1, *xs2, *xs3;
  int aw0, aw1, aw2, aw3;
#define APREP(J, XS, AW) { int c = (J) * 256 + tid; int m = c >> 3, kg8 = c & 7;       \
    XS = X + (m0 + m) * 1024 + kg8 * 8;                                                \
    int kt2 = kg8 >> 2, ks = kg8 & 3, msub = m >> 4, mm = m & 15;                      \
    AW = (((kt2 * 8 + msub) * 64 + ks * 16 + mm) * 16) ^ (ks << 4); }
  APREP(0, xs0, aw0) APREP(1, xs1, aw1) APREP(2, xs2, aw2) APREP(3, xs3, aw3)
#undef APREP

  const u16* wsrc0 = Wf + (size_t)ni * 4096 + tid * 8;
  u16* bd0 = Bs + tid * 8;
  const int aro = (lane * 16) ^ (((lane >> 4) & 3) << 4);
  const char* Ab = (const char*)As + aro;
  const char* Bb = (const char*)Bs + lane * 16;

  f32x4 acc[4][4];
#pragma unroll
  for (int m = 0; m < 4; ++m)
#pragma unroll
    for (int n = 0; n < 4; ++n) acc[m][n] = {0.f, 0.f, 0.f, 0.f};

  for (int it = 0; it < 16; ++it) {
    const u16* w0 = wsrc0 + (size_t)it * 65536;
    GL_LDS16(w0,          bd0);
    GL_LDS16(w0 + 2048,   bd0 + 2048);
    GL_LDS16(w0 + 32768,  bd0 + 4096);
    GL_LDS16(w0 + 34816,  bd0 + 6144);
    const int ko = it * 64;
#define ASTAGE(XS, AW) { f32x4 u = *(const f32x4*)((XS) + ko); f32x4 v = *(const f32x4*)((XS) + ko + 4); \
    u16x8 h;                                                                              \
    h[0] = cvtbf(u[0]); h[1] = cvtbf(u[1]); h[2] = cvtbf(u[2]); h[3] = cvtbf(u[3]);       \
    h[4] = cvtbf(v[0]); h[5] = cvtbf(v[1]); h[6] = cvtbf(v[2]); h[7] = cvtbf(v[3]);       \
    *(u16x8*)((char*)As + (AW)) = h; }
    ASTAGE(xs0, aw0) ASTAGE(xs1, aw1) ASTAGE(xs2, aw2) ASTAGE(xs3, aw3)
#undef ASTAGE
    __syncthreads();
#pragma unroll
    for (int kt2 = 0; kt2 < 2; ++kt2) {
      s16x8 af[4], bfr[4];
#pragma unroll
      for (int m = 0; m < 4; ++m) af[m] = *(const s16x8*)(Ab + ((kt2 * 8 + wr * 4 + m) << 10));
#pragma unroll
      for (int n = 0; n < 4; ++n) bfr[n] = *(const s16x8*)(Bb + ((kt2 * 8 + wc * 4 + n) << 10));
#pragma unroll
      for (int m = 0; m < 4; ++m)
#pragma unroll
        for (int n = 0; n < 4; ++n)
          acc[m][n] = __builtin_amdgcn_mfma_f32_16x16x32_bf16(af[m], bfr[n], acc[m][n], 0, 0, 0);
    }
    __syncthreads();
  }

  const long orow0 = m0 + wr * 64 + (lane >> 4) * 4;
  const int  ocol0 = n0 + wc * 64 + (lane & 15);
#pragma unroll
  for (int n = 0; n < 4; ++n) {
    const int cc = ocol0 + n * 16;
    const float bb = bvec[cc];
#pragma unroll
    for (int m = 0; m < 4; ++m) {
      const long r = orow0 + m * 16;
#pragma unroll
      for (int q = 0; q < 4; ++q)
        out[(r + q) * 1024 + cc] = acc[m][n][q] + bb;
    }
  }
}

extern "C" void kernel_launch(void* const* d_in, const int* in_sizes, int n_in,
                              void* d_out, int out_size, void* d_ws, size_t ws_size,
                              hipStream_t stream) {
  const float* x  = (const float*)d_in[0];
  const float* A  = (const float*)d_in[1];
  const float* bv = (const float*)d_in[2];
  float* out = (float*)d_out;
  char* ws = (char*)d_ws;

  float* B   = (float*)(ws);                              // 4 MB, becomes Y after k_minv
  float* Y   = B;
  float* M   = (float*)(ws + (4u << 20));                 // 4 MB; upper triangle hosts U buffers
  u16*   Wf  = (u16*)  (ws + (8u << 20));                 // 2 MB
  float* rd2 = (float*)(ws + (10u << 20));                // 4 KB
  unsigned* FL = (unsigned*)(ws + (10u << 20) + 65536);   // 1 KB sync flags (zeroed by k_bbtx)
  u16*   Xbf = (u16*)  (ws + (12u << 20));                // 128 MB

  const size_t need = (12u << 20) + (size_t)65536 * 1024 * 2;
  const bool big = (ws_size >= need);

  k_bbtx<<<big ? 2184 : 136, 256, 0, stream>>>(A, B, rd2, M, FL, x, Xbf);
  k_minv<<<120, 256, 0, stream>>>(B, rd2, M, FL);
  k_yw<<<512, 256, 0, stream>>>(M, A, Y, rd2, Wf, FL);
  if (big) {
    k_out8<<<1024, 1024, 0, stream>>>(Xbf, Wf, bv, out);
  } else {
    k_out_r<<<4096, 256, 0, stream>>>(x, Wf, bv, out);
  }
}

// Round 11
// 481.169 us; speedup vs baseline: 1.3600x; 1.3600x over previous
//
#include <hip/hip_runtime.h>
#include <hip/hip_bf16.h>

typedef unsigned short u16;
typedef float f32x4 __attribute__((ext_vector_type(4)));
typedef u16   u16x8 __attribute__((ext_vector_type(8)));
typedef u16   u16x4 __attribute__((ext_vector_type(4)));
typedef short s16x8 __attribute__((ext_vector_type(8)));

__device__ __forceinline__ u16 f2bf(float f) {
  unsigned u = __builtin_bit_cast(unsigned, f);
  unsigned r = (u + 0x7fffu + ((u >> 16) & 1u)) >> 16;
  return (u16)r;
}
__device__ __forceinline__ u16 cvtbf(float f) {
  return __builtin_bit_cast(u16, __float2bfloat16(f));
}

#define GL_LDS16(gp, lp)                                                     \
  __builtin_amdgcn_global_load_lds((const __attribute__((address_space(1))) void*)(gp), \
                                   (__attribute__((address_space(3))) void*)(lp), 16, 0, 0)

// ===== K1: B=A*A^T (136 sym tiles, mirrored) + rd2 + diag 64-inverses -> M + Xbf convert =====
__global__ __launch_bounds__(256) void k_bbtx(const float* __restrict__ A, float* __restrict__ B,
                                              float* __restrict__ rd2, float* __restrict__ M,
                                              const float* __restrict__ X, u16* __restrict__ Xbf) {
  const int bid = blockIdx.x;
  const int tid = threadIdx.x;
  if (bid >= 136) {
    // X fp32 -> bf16 in A-fragment order: [mi256][half(32)][msub(16)][lane(64)][8]
    for (int gid = (bid - 136) * 256 + tid; gid < (1 << 23); gid += 2048 * 256) {
      const int mi   = gid >> 15;
      const int half = (gid >> 10) & 31;
      const int msub = (gid >> 6) & 15;
      const int lane = gid & 63;
      const int m = mi * 256 + msub * 16 + (lane & 15);
      const int k = half * 32 + (lane >> 4) * 8;
      const float* s = X + (size_t)m * 1024 + k;
      f32x4 u = *(const f32x4*)s;
      f32x4 v = *(const f32x4*)(s + 4);
      u16x8 h;
      h[0] = cvtbf(u[0]); h[1] = cvtbf(u[1]); h[2] = cvtbf(u[2]); h[3] = cvtbf(u[3]);
      h[4] = cvtbf(v[0]); h[5] = cvtbf(v[1]); h[6] = cvtbf(v[2]); h[7] = cvtbf(v[3]);
      *(u16x8*)(Xbf + (size_t)gid * 8) = h;
    }
    return;
  }
  __shared__ float s0[32][68];
  __shared__ float s1[32][68];
  __shared__ float Ct[64][68];
  __shared__ float rdl[64];

  int t = bid, ii = 0;
  while (t >= 16 - ii) { t -= 16 - ii; ++ii; }
  const int jj = ii + t;
  const int i0 = ii * 64, j0 = jj * 64;
  const int tx = tid & 15, ty = tid >> 4;
  const int sr = tid >> 2, sc = (tid & 3) * 8;
  f32x4 acc[4];
#pragma unroll
  for (int q = 0; q < 4; ++q) acc[q] = {0.f, 0.f, 0.f, 0.f};

  for (int k0 = 0; k0 < 1024; k0 += 32) {
    f32x4 a0 = *(const f32x4*)&A[(size_t)(i0 + sr) * 1024 + k0 + sc];
    f32x4 a1 = *(const f32x4*)&A[(size_t)(i0 + sr) * 1024 + k0 + sc + 4];
    f32x4 b0 = *(const f32x4*)&A[(size_t)(j0 + sr) * 1024 + k0 + sc];
    f32x4 b1 = *(const f32x4*)&A[(size_t)(j0 + sr) * 1024 + k0 + sc + 4];
    __syncthreads();
#pragma unroll
    for (int q = 0; q < 4; ++q) {
      s0[sc + q][sr] = a0[q]; s0[sc + 4 + q][sr] = a1[q];
      s1[sc + q][sr] = b0[q]; s1[sc + 4 + q][sr] = b1[q];
    }
    __syncthreads();
#pragma unroll
    for (int kk = 0; kk < 32; ++kk) {
      f32x4 av = *(const f32x4*)&s0[kk][ty * 4];
      f32x4 bv = *(const f32x4*)&s1[kk][tx * 4];
#pragma unroll
      for (int q = 0; q < 4; ++q) acc[q] += bv * av[q];
    }
  }
#pragma unroll
  for (int q = 0; q < 4; ++q)
    *(f32x4*)&B[(size_t)(i0 + ty * 4 + q) * 1024 + j0 + tx * 4] = acc[q];

  if (ii != jj) {
#pragma unroll
    for (int q = 0; q < 4; ++q)
#pragma unroll
      for (int w = 0; w < 4; ++w)
        B[(size_t)(j0 + tx * 4 + w) * 1024 + i0 + ty * 4 + q] = acc[q][w];
    return;
  }
  // diagonal block: rd2 + 64x64 inverse T = (I+L)^-1 -> M diagonal
  if (tx == ty) {
#pragma unroll
    for (int q = 0; q < 4; ++q) {
      float v = 2.0f / acc[q][q];
      rdl[ty * 4 + q] = v;
      rd2[i0 + ty * 4 + q] = v;
    }
  }
  __syncthreads();
#pragma unroll
  for (int q = 0; q < 4; ++q)
#pragma unroll
    for (int j = 0; j < 4; ++j) {
      int r = ty * 4 + q, c = tx * 4 + j;
      Ct[r][c] = (c > r) ? acc[q][j] * rdl[c] : 0.0f;
    }
  __syncthreads();
  if (tid < 64) {
    float pc[64];
#pragma unroll
    for (int r = 0; r < 64; ++r) pc[r] = (r == tid) ? 1.0f : 0.0f;
#pragma unroll
    for (int i = 0; i < 63; ++i) {
      const float pi = pc[i];
#pragma unroll
      for (int j = i + 1; j < 64; ++j) pc[j] -= Ct[i][j] * pi;
    }
#pragma unroll
    for (int r = 0; r < 64; ++r) M[(size_t)(i0 + r) * 1024 + i0 + tid] = pc[r];
  }
}

// ===== level 0 fused: per pair p, U = Cs*M11 (LDS), then M21 = -M22*U =====
__global__ __launch_bounds__(256) void k_lvl0(const float* __restrict__ B, const float* __restrict__ rd2,
                                              float* __restrict__ M) {
  __shared__ float sA[32][68];
  __shared__ float sB[32][68];
  __shared__ float Us[64][68];
  const int tid = threadIdx.x;
  const int a = blockIdx.x * 128;
  const int m0 = a + 64;
  const int tx = tid & 15, ty = tid >> 4;
  const int asr = tid >> 2, asc = (tid & 3) * 8;
  const int bkr = tid >> 3, bnc = (tid & 7) * 8;
  const float r2 = rd2[m0 + asr];
  f32x4 acc[4];
#pragma unroll
  for (int q = 0; q < 4; ++q) acc[q] = {0.f, 0.f, 0.f, 0.f};
  for (int k0 = 0; k0 < 64; k0 += 32) {
    f32x4 a0 = *(const f32x4*)&B[(size_t)(m0 + asr) * 1024 + a + k0 + asc];
    f32x4 a1 = *(const f32x4*)&B[(size_t)(m0 + asr) * 1024 + a + k0 + asc + 4];
    f32x4 b0 = *(const f32x4*)&M[(size_t)(a + k0 + bkr) * 1024 + a + bnc];
    f32x4 b1 = *(const f32x4*)&M[(size_t)(a + k0 + bkr) * 1024 + a + bnc + 4];
    a0 *= r2; a1 *= r2;
    __syncthreads();
#pragma unroll
    for (int q = 0; q < 4; ++q) { sA[asc + q][asr] = a0[q]; sA[asc + 4 + q][asr] = a1[q]; }
    *(f32x4*)&sB[bkr][bnc] = b0;
    *(f32x4*)&sB[bkr][bnc + 4] = b1;
    __syncthreads();
#pragma unroll
    for (int kk = 0; kk < 32; ++kk) {
      f32x4 av = *(const f32x4*)&sA[kk][ty * 4];
      f32x4 bv = *(const f32x4*)&sB[kk][tx * 4];
#pragma unroll
      for (int q = 0; q < 4; ++q) acc[q] += bv * av[q];
    }
  }
#pragma unroll
  for (int q = 0; q < 4; ++q) *(f32x4*)&Us[ty * 4 + q][tx * 4] = acc[q];
#pragma unroll
  for (int q = 0; q < 4; ++q) acc[q] = {0.f, 0.f, 0.f, 0.f};
  for (int k0 = 0; k0 < 64; k0 += 32) {
    f32x4 a0 = *(const f32x4*)&M[(size_t)(m0 + asr) * 1024 + m0 + k0 + asc];
    f32x4 a1 = *(const f32x4*)&M[(size_t)(m0 + asr) * 1024 + m0 + k0 + asc + 4];
    __syncthreads();   // also publishes Us writes on first iteration
#pragma unroll
    for (int q = 0; q < 4; ++q) { sA[asc + q][asr] = a0[q]; sA[asc + 4 + q][asr] = a1[q]; }
    __syncthreads();
#pragma unroll
    for (int kk = 0; kk < 32; ++kk) {
      f32x4 av = *(const f32x4*)&sA[kk][ty * 4];
      f32x4 bv = *(const f32x4*)&Us[k0 + kk][tx * 4];
#pragma unroll
      for (int q = 0; q < 4; ++q) acc[q] += bv * av[q];
    }
  }
#pragma unroll
  for (int q = 0; q < 4; ++q)
    *(f32x4*)&M[(size_t)(m0 + ty * 4 + q) * 1024 + a + tx * 4] = -acc[q];
}

// ===== level GEMM 1 (lvl>=1): U_p = Cscaled * M11, triangular skip =====
__global__ __launch_bounds__(256) void k_u(const float* __restrict__ B, const float* __restrict__ rd2,
                                           const float* __restrict__ M, float* __restrict__ U, int lvl) {
  __shared__ float sA[32][68];
  __shared__ float sB[32][68];
  const int tid = threadIdx.x;
  const int s = 64 << lvl;
  const int ti = blockIdx.x >> lvl, tj = blockIdx.x & ((1 << lvl) - 1);
  const int a = blockIdx.y * (s << 1);
  const int m0 = a + s + ti * 64;
  const int n0 = a + tj * 64;
  const int tx = tid & 15, ty = tid >> 4;
  const int asr = tid >> 2, asc = (tid & 3) * 8;
  const int bkr = tid >> 3, bnc = (tid & 7) * 8;
  const float r2 = rd2[m0 + asr];
  f32x4 acc[4];
#pragma unroll
  for (int q = 0; q < 4; ++q) acc[q] = {0.f, 0.f, 0.f, 0.f};

  for (int k0 = tj * 64; k0 < s; k0 += 32) {
    f32x4 a0 = *(const f32x4*)&B[(size_t)(m0 + asr) * 1024 + a + k0 + asc];
    f32x4 a1 = *(const f32x4*)&B[(size_t)(m0 + asr) * 1024 + a + k0 + asc + 4];
    f32x4 b0 = *(const f32x4*)&M[(size_t)(a + k0 + bkr) * 1024 + n0 + bnc];
    f32x4 b1 = *(const f32x4*)&M[(size_t)(a + k0 + bkr) * 1024 + n0 + bnc + 4];
    a0 *= r2; a1 *= r2;
    __syncthreads();
#pragma unroll
    for (int q = 0; q < 4; ++q) { sA[asc + q][asr] = a0[q]; sA[asc + 4 + q][asr] = a1[q]; }
    *(f32x4*)&sB[bkr][bnc] = b0;
    *(f32x4*)&sB[bkr][bnc + 4] = b1;
    __syncthreads();
#pragma unroll
    for (int kk = 0; kk < 32; ++kk) {
      f32x4 av = *(const f32x4*)&sA[kk][ty * 4];
      f32x4 bv = *(const f32x4*)&sB[kk][tx * 4];
#pragma unroll
      for (int q = 0; q < 4; ++q) acc[q] += bv * av[q];
    }
  }
  float* up = U + (size_t)blockIdx.y * s * s;
#pragma unroll
  for (int q = 0; q < 4; ++q)
    *(f32x4*)&up[(size_t)(ti * 64 + ty * 4 + q) * s + tj * 64 + tx * 4] = acc[q];
}

// ===== level GEMM 2: M21 = -M22*U, triangular skip =====
__global__ __launch_bounds__(256) void k_moff(float* __restrict__ M, const float* __restrict__ U, int lvl) {
  __shared__ float sA[32][68];
  __shared__ float sB[32][68];
  const int tid = threadIdx.x;
  const int s = 64 << lvl;
  const int ti = blockIdx.x >> lvl, tj = blockIdx.x & ((1 << lvl) - 1);
  const int a = blockIdx.y * (s << 1);
  const int m0 = a + s + ti * 64;
  const int n0 = a + tj * 64;
  const int tx = tid & 15, ty = tid >> 4;
  const int asr = tid >> 2, asc = (tid & 3) * 8;
  const int bkr = tid >> 3, bnc = (tid & 7) * 8;
  const float* up = U + (size_t)blockIdx.y * s * s;
  const int kmax = (ti + 1) * 64;
  f32x4 acc[4];
#pragma unroll
  for (int q = 0; q < 4; ++q) acc[q] = {0.f, 0.f, 0.f, 0.f};

  for (int k0 = 0; k0 < kmax; k0 += 32) {
    f32x4 a0 = *(const f32x4*)&M[(size_t)(m0 + asr) * 1024 + a + s + k0 + asc];
    f32x4 a1 = *(const f32x4*)&M[(size_t)(m0 + asr) * 1024 + a + s + k0 + asc + 4];
    f32x4 b0 = *(const f32x4*)&up[(size_t)(k0 + bkr) * s + tj * 64 + bnc];
    f32x4 b1 = *(const f32x4*)&up[(size_t)(k0 + bkr) * s + tj * 64 + bnc + 4];
    __syncthreads();
#pragma unroll
    for (int q = 0; q < 4; ++q) { sA[asc + q][asr] = a0[q]; sA[asc + 4 + q][asr] = a1[q]; }
    *(f32x4*)&sB[bkr][bnc] = b0;
    *(f32x4*)&sB[bkr][bnc + 4] = b1;
    __syncthreads();
#pragma unroll
    for (int kk = 0; kk < 32; ++kk) {
      f32x4 av = *(const f32x4*)&sA[kk][ty * 4];
      f32x4 bv = *(const f32x4*)&sB[kk][tx * 4];
#pragma unroll
      for (int q = 0; q < 4; ++q) acc[q] += bv * av[q];
    }
  }
#pragma unroll
  for (int q = 0; q < 4; ++q)
    *(f32x4*)&M[(size_t)(m0 + ty * 4 + q) * 1024 + n0 + tx * 4] = -acc[q];
}

// ===== Y = M * A (triangular K-skip) =====
__global__ __launch_bounds__(256) void k_yma(const float* __restrict__ M, const float* __restrict__ A,
                                             float* __restrict__ Y) {
  __shared__ float sA[32][68];
  __shared__ float sB[32][68];
  const int tid = threadIdx.x;
  const int ri = blockIdx.y, cj = blockIdx.x;
  const int m0 = ri * 64, n0 = cj * 64;
  const int kmax = (ri + 1) * 64;
  const int tx = tid & 15, ty = tid >> 4;
  const int asr = tid >> 2, asc = (tid & 3) * 8;
  const int bkr = tid >> 3, bnc = (tid & 7) * 8;
  f32x4 acc[4];
#pragma unroll
  for (int q = 0; q < 4; ++q) acc[q] = {0.f, 0.f, 0.f, 0.f};

  for (int k0 = 0; k0 < kmax; k0 += 32) {
    f32x4 a0 = *(const f32x4*)&M[(size_t)(m0 + asr) * 1024 + k0 + asc];
    f32x4 a1 = *(const f32x4*)&M[(size_t)(m0 + asr) * 1024 + k0 + asc + 4];
    f32x4 b0 = *(const f32x4*)&A[(size_t)(k0 + bkr) * 1024 + n0 + bnc];
    f32x4 b1 = *(const f32x4*)&A[(size_t)(k0 + bkr) * 1024 + n0 + bnc + 4];
    __syncthreads();
#pragma unroll
    for (int q = 0; q < 4; ++q) { sA[asc + q][asr] = a0[q]; sA[asc + 4 + q][asr] = a1[q]; }
    *(f32x4*)&sB[bkr][bnc] = b0;
    *(f32x4*)&sB[bkr][bnc + 4] = b1;
    __syncthreads();
#pragma unroll
    for (int kk = 0; kk < 32; ++kk) {
      f32x4 av = *(const f32x4*)&sA[kk][ty * 4];
      f32x4 bv = *(const f32x4*)&sB[kk][tx * 4];
#pragma unroll
      for (int q = 0; q < 4; ++q) acc[q] += bv * av[q];
    }
  }
#pragma unroll
  for (int q = 0; q < 4; ++q)
    *(f32x4*)&Y[(size_t)(m0 + ty * 4 + q) * 1024 + n0 + tx * 4] = acc[q];
}

// ===== Wf in MFMA-B-fragment order =====
__global__ __launch_bounds__(256) void k_w(const float* __restrict__ A, const float* __restrict__ P,
                                           const float* __restrict__ rd2, u16* __restrict__ Wf) {
  __shared__ float As[32][68];
  __shared__ float Ps[32][68];
  const int tid = threadIdx.x;
  const int kb = blockIdx.y * 64, nb = blockIdx.x * 64;
  const int sr = tid >> 3, sc = (tid & 7) * 8;
  const int tx = tid & 15, ty = tid >> 4;
  f32x4 acc[4];
#pragma unroll
  for (int q = 0; q < 4; ++q) acc[q] = {0.f, 0.f, 0.f, 0.f};

  for (int i0 = 0; i0 < 1024; i0 += 32) {
    float r2 = rd2[i0 + sr];
    f32x4 a0 = *(const f32x4*)&A[(size_t)(i0 + sr) * 1024 + kb + sc];
    f32x4 a1 = *(const f32x4*)&A[(size_t)(i0 + sr) * 1024 + kb + sc + 4];
    f32x4 p0 = *(const f32x4*)&P[(size_t)(i0 + sr) * 1024 + nb + sc];
    f32x4 p1 = *(const f32x4*)&P[(size_t)(i0 + sr) * 1024 + nb + sc + 4];
    __syncthreads();
    *(f32x4*)&As[sr][sc]     = a0 * r2;
    *(f32x4*)&As[sr][sc + 4] = a1 * r2;
    *(f32x4*)&Ps[sr][sc]     = p0;
    *(f32x4*)&Ps[sr][sc + 4] = p1;
    __syncthreads();
#pragma unroll
    for (int i = 0; i < 32; ++i) {
      f32x4 av = *(const f32x4*)&As[i][ty * 4];
      f32x4 pv = *(const f32x4*)&Ps[i][tx * 4];
#pragma unroll
      for (int q = 0; q < 4; ++q) acc[q] += pv * av[q];
    }
  }
  const int ktile = (kb + ty * 4) >> 5;
  const int kg = ((ty * 4) >> 3) & 3;
  const int e0 = (ty * 4) & 7;
#pragma unroll
  for (int j = 0; j < 4; ++j) {
    int n = nb + tx * 4 + j;
    int nt = n >> 4;
    int ln = kg * 16 + (n & 15);
    u16x4 pk;
#pragma unroll
    for (int q = 0; q < 4; ++q) {
      int kk = kb + ty * 4 + q;
      float w = ((kk == n) ? 1.0f : 0.0f) - acc[q][j];
      pk[q] = f2bf(w);
    }
    *(u16x4*)&Wf[((size_t)(ktile * 64 + nt) * 64 + ln) * 8 + e0] = pk;
  }
}

// ===== 256x256 GEMM, 16 waves (4x4), 64x64/wave, 4 waves/SIMD, counted-vmcnt depth-3 =====
template<int I>
__device__ __forceinline__ void phase_body(const u16* __restrict__ ax, const u16* __restrict__ wbase,
                                           u16* As, u16* Bs, int tid, int wr, int wc, int lane,
                                           f32x4 (&acc)[4][4]) {
  if constexpr (I <= 29)      asm volatile("s_waitcnt vmcnt(4)" ::: "memory");
  else if constexpr (I == 30) asm volatile("s_waitcnt vmcnt(2)" ::: "memory");
  else                        asm volatile("s_waitcnt vmcnt(0)" ::: "memory");
  __builtin_amdgcn_s_barrier();   // unconditional: all waves' half-I loads landed
  if constexpr (I + 3 < 32) {     // prefetch half I+3 into slot (I+3)&3 (its reads ended phase I-1)
    constexpr int j = I + 3, js = j & 3;
    GL_LDS16(ax + (size_t)j * 8192 + tid * 8,     As + js * 8192 + tid * 8);
    GL_LDS16(wbase + (size_t)j * 32768 + tid * 8, Bs + js * 8192 + tid * 8);
  }
  const u16* Asb = As + (I & 3) * 8192;
  const u16* Bsb = Bs + (I & 3) * 8192;
  s16x8 af[4], bf[4];
#pragma unroll
  for (int m = 0; m < 4; ++m) af[m] = *(const s16x8*)&Asb[(wr * 4 + m) * 512 + lane * 8];
#pragma unroll
  for (int n = 0; n < 4; ++n) bf[n] = *(const s16x8*)&Bsb[(wc * 4 + n) * 512 + lane * 8];
  __builtin_amdgcn_s_setprio(1);
#pragma unroll
  for (int m = 0; m < 4; ++m)
#pragma unroll
    for (int n = 0; n < 4; ++n)
      acc[m][n] = __builtin_amdgcn_mfma_f32_16x16x32_bf16(af[m], bf[n], acc[m][n], 0, 0, 0);
  __builtin_amdgcn_s_setprio(0);
}

__global__ __launch_bounds__(1024, 4) void k_out8(const u16* __restrict__ Xbf, const u16* __restrict__ Wf,
                                                  const float* __restrict__ bvec, float* __restrict__ out) {
  __shared__ u16 As[32768];   // 4 slots x 16KB (A half: 256 rows x 32 k bf16)
  __shared__ u16 Bs[32768];   // 4 slots x 16KB (B half)
  const int tid = threadIdx.x;
  const int lane = tid & 63, wid = tid >> 6;
  const int wr = wid >> 2, wc = wid & 3;          // 4M x 4N waves; per-wave out 64x64
  const int lin = blockIdx.x;
  const int xcd = lin & 7, idx = lin >> 3;
  const int mi = xcd * 32 + (idx >> 2);           // XCD-chunked
  const int ni = idx & 3;

  const u16* ax = Xbf + (size_t)mi * 262144;      // per half: 8192 u16 (16KB)
  const u16* wbase = Wf + (size_t)ni * 8192;      // per half: +32768 u16

  f32x4 acc[4][4];
#pragma unroll
  for (int m = 0; m < 4; ++m)
#pragma unroll
    for (int n = 0; n < 4; ++n) acc[m][n] = {0.f, 0.f, 0.f, 0.f};

  // prologue: issue halves 0,1,2 (A+B each, 1 load/thread each)
#pragma unroll
  for (int j = 0; j < 3; ++j) {
    GL_LDS16(ax + (size_t)j * 8192 + tid * 8,     As + j * 8192 + tid * 8);
    GL_LDS16(wbase + (size_t)j * 32768 + tid * 8, Bs + j * 8192 + tid * 8);
  }

#define PH(I) phase_body<I>(ax, wbase, As, Bs, tid, wr, wc, lane, acc);
  PH(0)  PH(1)  PH(2)  PH(3)  PH(4)  PH(5)  PH(6)  PH(7)
  PH(8)  PH(9)  PH(10) PH(11) PH(12) PH(13) PH(14) PH(15)
  PH(16) PH(17) PH(18) PH(19) PH(20) PH(21) PH(22) PH(23)
  PH(24) PH(25) PH(26) PH(27) PH(28) PH(29) PH(30) PH(31)
#undef PH

  const long orow0 = (long)mi * 256 + wr * 64 + (lane >> 4) * 4;
  const int  ocol0 = ni * 256 + wc * 64 + (lane & 15);
#pragma unroll
  for (int aj = 0; aj < 4; ++aj) {
    const int cc = ocol0 + aj * 16;
    const float bb = bvec[cc];
#pragma unroll
    for (int ai = 0; ai < 4; ++ai) {
      const long r = orow0 + ai * 16;
#pragma unroll
      for (int q = 0; q < 4; ++q)
        out[(r + q) * 1024 + cc] = acc[ai][aj][q] + bb;
    }
  }
}

// ===== fallback GEMM (reg-staged A) if workspace too small for Xbf =====
__global__ __launch_bounds__(256) void k_out_r(const float* __restrict__ X, const u16* __restrict__ Wf,
                                               const float* __restrict__ bvec, float* __restrict__ out) {
  __shared__ u16 As[8192];
  __shared__ u16 Bs[8192];
  const int tid = threadIdx.x;
  const int lane = tid & 63, wid = tid >> 6;
  const int wr = wid >> 1, wc = wid & 1;
  const int lin = blockIdx.x;
  const int mi = (lin & 7) * 64 + (lin >> 6);
  const int ni = (lin >> 3) & 7;
  const long m0 = (long)mi * 128;
  const int n0 = ni * 128;

  const float *xs0, *xs1, *xs2, *xs3;
  int aw0, aw1, aw2, aw3;
#define APREP(J, XS, AW) { int c = (J) * 256 + tid; int m = c >> 3, kg8 = c & 7;       \
    XS = X + (m0 + m) * 1024 + kg8 * 8;                                                \
    int kt2 = kg8 >> 2, ks = kg8 & 3, msub = m >> 4, mm = m & 15;                      \
    AW = (((kt2 * 8 + msub) * 64 + ks * 16 + mm) * 16) ^ (ks << 4); }
  APREP(0, xs0, aw0) APREP(1, xs1, aw1) APREP(2, xs2, aw2) APREP(3, xs3, aw3)
#undef APREP

  const u16* wsrc0 = Wf + (size_t)ni * 4096 + tid * 8;
  u16* bd0 = Bs + tid * 8;
  const int aro = (lane * 16) ^ (((lane >> 4) & 3) << 4);
  const char* Ab = (const char*)As + aro;
  const char* Bb = (const char*)Bs + lane * 16;

  f32x4 acc[4][4];
#pragma unroll
  for (int m = 0; m < 4; ++m)
#pragma unroll
    for (int n = 0; n < 4; ++n) acc[m][n] = {0.f, 0.f, 0.f, 0.f};

  for (int it = 0; it < 16; ++it) {
    const u16* w0 = wsrc0 + (size_t)it * 65536;
    GL_LDS16(w0,          bd0);
    GL_LDS16(w0 + 2048,   bd0 + 2048);
    GL_LDS16(w0 + 32768,  bd0 + 4096);
    GL_LDS16(w0 + 34816,  bd0 + 6144);
    const int ko = it * 64;
#define ASTAGE(XS, AW) { f32x4 u = *(const f32x4*)((XS) + ko); f32x4 v = *(const f32x4*)((XS) + ko + 4); \
    u16x8 h;                                                                              \
    h[0] = cvtbf(u[0]); h[1] = cvtbf(u[1]); h[2] = cvtbf(u[2]); h[3] = cvtbf(u[3]);       \
    h[4] = cvtbf(v[0]); h[5] = cvtbf(v[1]); h[6] = cvtbf(v[2]); h[7] = cvtbf(v[3]);       \
    *(u16x8*)((char*)As + (AW)) = h; }
    ASTAGE(xs0, aw0) ASTAGE(xs1, aw1) ASTAGE(xs2, aw2) ASTAGE(xs3, aw3)
#undef ASTAGE
    __syncthreads();
#pragma unroll
    for (int kt2 = 0; kt2 < 2; ++kt2) {
      s16x8 af[4], bfr[4];
#pragma unroll
      for (int m = 0; m < 4; ++m) af[m] = *(const s16x8*)(Ab + ((kt2 * 8 + wr * 4 + m) << 10));
#pragma unroll
      for (int n = 0; n < 4; ++n) bfr[n] = *(const s16x8*)(Bb + ((kt2 * 8 + wc * 4 + n) << 10));
#pragma unroll
      for (int m = 0; m < 4; ++m)
#pragma unroll
        for (int n = 0; n < 4; ++n)
          acc[m][n] = __builtin_amdgcn_mfma_f32_16x16x32_bf16(af[m], bfr[n], acc[m][n], 0, 0, 0);
    }
    __syncthreads();
  }

  const long orow0 = m0 + wr * 64 + (lane >> 4) * 4;
  const int  ocol0 = n0 + wc * 64 + (lane & 15);
#pragma unroll
  for (int n = 0; n < 4; ++n) {
    const int cc = ocol0 + n * 16;
    const float bb = bvec[cc];
#pragma unroll
    for (int m = 0; m < 4; ++m) {
      const long r = orow0 + m * 16;
#pragma unroll
      for (int q = 0; q < 4; ++q)
        out[(r + q) * 1024 + cc] = acc[m][n][q] + bb;
    }
  }
}

extern "C" void kernel_launch(void* const* d_in, const int* in_sizes, int n_in,
                              void* d_out, int out_size, void* d_ws, size_t ws_size,
                              hipStream_t stream) {
  const float* x  = (const float*)d_in[0];
  const float* A  = (const float*)d_in[1];
  const float* bv = (const float*)d_in[2];
  float* out = (float*)d_out;
  char* ws = (char*)d_ws;

  float* B   = (float*)(ws);                              // 4 MB, becomes Y
  float* Y   = B;
  float* M   = (float*)(ws + (4u << 20));                 // 4 MB
  u16*   Wf  = (u16*)  (ws + (8u << 20));                 // 2 MB
  float* rd2 = (float*)(ws + (10u << 20));                // 4 KB
  float* U   = (float*)(ws + (10u << 20) + 65536);        // 1 MB
  u16*   Xbf = (u16*)  (ws + (12u << 20));                // 128 MB

  const size_t need = (12u << 20) + (size_t)65536 * 1024 * 2;
  const bool big = (ws_size >= need);

  k_bbtx<<<big ? 2184 : 136, 256, 0, stream>>>(A, B, rd2, M, x, Xbf);
  k_lvl0<<<8, 256, 0, stream>>>(B, rd2, M);
  for (int lvl = 1; lvl < 4; ++lvl) {
    const int nt2 = 1 << (2 * lvl);
    const int np  = 8 >> lvl;
    k_u<<<dim3(nt2, np), 256, 0, stream>>>(B, rd2, M, U, lvl);
    k_moff<<<dim3(nt2, np), 256, 0, stream>>>(M, U, lvl);
  }
  k_yma<<<dim3(16, 16), 256, 0, stream>>>(M, A, Y);
  k_w<<<dim3(16, 16), 256, 0, stream>>>(A, Y, rd2, Wf);

  if (big) {
    k_out8<<<1024, 1024, 0, stream>>>(Xbf, Wf, bv, out);
  } else {
    k_out_r<<<4096, 256, 0, stream>>>(x, Wf, bv, out);
  }
}

// Round 12
// 475.762 us; speedup vs baseline: 1.3755x; 1.0114x over previous
//
#include <hip/hip_runtime.h>
#include <hip/hip_bf16.h>

typedef unsigned short u16;
typedef float f32x4 __attribute__((ext_vector_type(4)));
typedef u16   u16x8 __attribute__((ext_vector_type(8)));
typedef u16   u16x4 __attribute__((ext_vector_type(4)));
typedef short s16x8 __attribute__((ext_vector_type(8)));

__device__ __forceinline__ u16 f2bf(float f) {
  unsigned u = __builtin_bit_cast(unsigned, f);
  unsigned r = (u + 0x7fffu + ((u >> 16) & 1u)) >> 16;
  return (u16)r;
}
__device__ __forceinline__ u16 cvtbf(float f) {
  return __builtin_bit_cast(u16, __float2bfloat16(f));
}

#define GL_LDS16(gp, lp)                                                     \
  __builtin_amdgcn_global_load_lds((const __attribute__((address_space(1))) void*)(gp), \
                                   (__attribute__((address_space(3))) void*)(lp), 16, 0, 0)

// ---- X fp32 -> bf16 slice converter (A-fragment order: [mi256][half(32)][msub(16)][lane(64)][8]) ----
// No LDS use: safe to co-locate with LDS-bound blocks.
__device__ __forceinline__ void conv_slice(const float* __restrict__ X, u16* __restrict__ Xbf,
                                           int cb, int nblocks, int lo, int hi) {
  for (int gid = lo + cb * 256 + (int)threadIdx.x; gid < hi; gid += nblocks * 256) {
    const int mi   = gid >> 15;
    const int half = (gid >> 10) & 31;
    const int msub = (gid >> 6) & 15;
    const int lane = gid & 63;
    const int m = mi * 256 + msub * 16 + (lane & 15);
    const int k = half * 32 + (lane >> 4) * 8;
    const float* s = X + (size_t)m * 1024 + k;
    f32x4 u = *(const f32x4*)s;
    f32x4 v = *(const f32x4*)(s + 4);
    u16x8 h;
    h[0] = cvtbf(u[0]); h[1] = cvtbf(u[1]); h[2] = cvtbf(u[2]); h[3] = cvtbf(u[3]);
    h[4] = cvtbf(v[0]); h[5] = cvtbf(v[1]); h[6] = cvtbf(v[2]); h[7] = cvtbf(v[3]);
    *(u16x8*)(Xbf + (size_t)gid * 8) = h;
  }
}

// ===== K1: B=A*A^T (136 sym tiles, mirrored) + rd2 + diag 64-inverses -> M ; + conv slice 0 =====
__global__ __launch_bounds__(256) void k_bbtx(const float* __restrict__ A, float* __restrict__ B,
                                              float* __restrict__ rd2, float* __restrict__ M,
                                              const float* __restrict__ X, u16* __restrict__ Xbf) {
  const int bid = blockIdx.x;
  const int tid = threadIdx.x;
  if (bid >= 136) { conv_slice(X, Xbf, bid - 136, 1024, 0, 4194304); return; }

  __shared__ float s0[32][68];
  __shared__ float s1[32][68];
  __shared__ float Ct[64][68];
  __shared__ float rdl[64];

  int t = bid, ii = 0;
  while (t >= 16 - ii) { t -= 16 - ii; ++ii; }
  const int jj = ii + t;
  const int i0 = ii * 64, j0 = jj * 64;
  const int tx = tid & 15, ty = tid >> 4;
  const int sr = tid >> 2, sc = (tid & 3) * 8;
  f32x4 acc[4];
#pragma unroll
  for (int q = 0; q < 4; ++q) acc[q] = {0.f, 0.f, 0.f, 0.f};

  for (int k0 = 0; k0 < 1024; k0 += 32) {
    f32x4 a0 = *(const f32x4*)&A[(size_t)(i0 + sr) * 1024 + k0 + sc];
    f32x4 a1 = *(const f32x4*)&A[(size_t)(i0 + sr) * 1024 + k0 + sc + 4];
    f32x4 b0 = *(const f32x4*)&A[(size_t)(j0 + sr) * 1024 + k0 + sc];
    f32x4 b1 = *(const f32x4*)&A[(size_t)(j0 + sr) * 1024 + k0 + sc + 4];
    __syncthreads();
#pragma unroll
    for (int q = 0; q < 4; ++q) {
      s0[sc + q][sr] = a0[q]; s0[sc + 4 + q][sr] = a1[q];
      s1[sc + q][sr] = b0[q]; s1[sc + 4 + q][sr] = b1[q];
    }
    __syncthreads();
#pragma unroll
    for (int kk = 0; kk < 32; ++kk) {
      f32x4 av = *(const f32x4*)&s0[kk][ty * 4];
      f32x4 bv = *(const f32x4*)&s1[kk][tx * 4];
#pragma unroll
      for (int q = 0; q < 4; ++q) acc[q] += bv * av[q];
    }
  }
#pragma unroll
  for (int q = 0; q < 4; ++q)
    *(f32x4*)&B[(size_t)(i0 + ty * 4 + q) * 1024 + j0 + tx * 4] = acc[q];

  if (ii != jj) {
#pragma unroll
    for (int q = 0; q < 4; ++q)
#pragma unroll
      for (int w = 0; w < 4; ++w)
        B[(size_t)(j0 + tx * 4 + w) * 1024 + i0 + ty * 4 + q] = acc[q][w];
    return;
  }
  // diagonal block: rd2 + 64x64 inverse T = (I+L)^-1 -> M diagonal
  if (tx == ty) {
#pragma unroll
    for (int q = 0; q < 4; ++q) {
      float v = 2.0f / acc[q][q];
      rdl[ty * 4 + q] = v;
      rd2[i0 + ty * 4 + q] = v;
    }
  }
  __syncthreads();
#pragma unroll
  for (int q = 0; q < 4; ++q)
#pragma unroll
    for (int j = 0; j < 4; ++j) {
      int r = ty * 4 + q, c = tx * 4 + j;
      Ct[r][c] = (c > r) ? acc[q][j] * rdl[c] : 0.0f;
    }
  __syncthreads();
  if (tid < 64) {
    float pc[64];
#pragma unroll
    for (int r = 0; r < 64; ++r) pc[r] = (r == tid) ? 1.0f : 0.0f;
#pragma unroll
    for (int i = 0; i < 63; ++i) {
      const float pi = pc[i];
#pragma unroll
      for (int j = i + 1; j < 64; ++j) pc[j] -= Ct[i][j] * pi;
    }
#pragma unroll
    for (int r = 0; r < 64; ++r) M[(size_t)(i0 + r) * 1024 + i0 + tid] = pc[r];
  }
}

// ===== level 0 fused: per pair p, U = Cs*M11 (LDS), then M21 = -M22*U =====
__global__ __launch_bounds__(256) void k_lvl0(const float* __restrict__ B, const float* __restrict__ rd2,
                                              float* __restrict__ M) {
  __shared__ float sA[32][68];
  __shared__ float sB[32][68];
  __shared__ float Us[64][68];
  const int tid = threadIdx.x;
  const int a = blockIdx.x * 128;
  const int m0 = a + 64;
  const int tx = tid & 15, ty = tid >> 4;
  const int asr = tid >> 2, asc = (tid & 3) * 8;
  const int bkr = tid >> 3, bnc = (tid & 7) * 8;
  const float r2 = rd2[m0 + asr];
  f32x4 acc[4];
#pragma unroll
  for (int q = 0; q < 4; ++q) acc[q] = {0.f, 0.f, 0.f, 0.f};
  for (int k0 = 0; k0 < 64; k0 += 32) {
    f32x4 a0 = *(const f32x4*)&B[(size_t)(m0 + asr) * 1024 + a + k0 + asc];
    f32x4 a1 = *(const f32x4*)&B[(size_t)(m0 + asr) * 1024 + a + k0 + asc + 4];
    f32x4 b0 = *(const f32x4*)&M[(size_t)(a + k0 + bkr) * 1024 + a + bnc];
    f32x4 b1 = *(const f32x4*)&M[(size_t)(a + k0 + bkr) * 1024 + a + bnc + 4];
    a0 *= r2; a1 *= r2;
    __syncthreads();
#pragma unroll
    for (int q = 0; q < 4; ++q) { sA[asc + q][asr] = a0[q]; sA[asc + 4 + q][asr] = a1[q]; }
    *(f32x4*)&sB[bkr][bnc] = b0;
    *(f32x4*)&sB[bkr][bnc + 4] = b1;
    __syncthreads();
#pragma unroll
    for (int kk = 0; kk < 32; ++kk) {
      f32x4 av = *(const f32x4*)&sA[kk][ty * 4];
      f32x4 bv = *(const f32x4*)&sB[kk][tx * 4];
#pragma unroll
      for (int q = 0; q < 4; ++q) acc[q] += bv * av[q];
    }
  }
#pragma unroll
  for (int q = 0; q < 4; ++q) *(f32x4*)&Us[ty * 4 + q][tx * 4] = acc[q];
#pragma unroll
  for (int q = 0; q < 4; ++q) acc[q] = {0.f, 0.f, 0.f, 0.f};
  for (int k0 = 0; k0 < 64; k0 += 32) {
    f32x4 a0 = *(const f32x4*)&M[(size_t)(m0 + asr) * 1024 + m0 + k0 + asc];
    f32x4 a1 = *(const f32x4*)&M[(size_t)(m0 + asr) * 1024 + m0 + k0 + asc + 4];
    __syncthreads();   // also publishes Us writes on first iteration
#pragma unroll
    for (int q = 0; q < 4; ++q) { sA[asc + q][asr] = a0[q]; sA[asc + 4 + q][asr] = a1[q]; }
    __syncthreads();
#pragma unroll
    for (int kk = 0; kk < 32; ++kk) {
      f32x4 av = *(const f32x4*)&sA[kk][ty * 4];
      f32x4 bv = *(const f32x4*)&Us[k0 + kk][tx * 4];
#pragma unroll
      for (int q = 0; q < 4; ++q) acc[q] += bv * av[q];
    }
  }
#pragma unroll
  for (int q = 0; q < 4; ++q)
    *(f32x4*)&M[(size_t)(m0 + ty * 4 + q) * 1024 + a + tx * 4] = -acc[q];
}

// ===== level GEMM 1 (lvl>=1): U_p = Cscaled * M11, triangular skip =====
__global__ __launch_bounds__(256) void k_u(const float* __restrict__ B, const float* __restrict__ rd2,
                                           const float* __restrict__ M, float* __restrict__ U, int lvl) {
  __shared__ float sA[32][68];
  __shared__ float sB[32][68];
  const int tid = threadIdx.x;
  const int s = 64 << lvl;
  const int ti = blockIdx.x >> lvl, tj = blockIdx.x & ((1 << lvl) - 1);
  const int a = blockIdx.y * (s << 1);
  const int m0 = a + s + ti * 64;
  const int n0 = a + tj * 64;
  const int tx = tid & 15, ty = tid >> 4;
  const int asr = tid >> 2, asc = (tid & 3) * 8;
  const int bkr = tid >> 3, bnc = (tid & 7) * 8;
  const float r2 = rd2[m0 + asr];
  f32x4 acc[4];
#pragma unroll
  for (int q = 0; q < 4; ++q) acc[q] = {0.f, 0.f, 0.f, 0.f};

  for (int k0 = tj * 64; k0 < s; k0 += 32) {
    f32x4 a0 = *(const f32x4*)&B[(size_t)(m0 + asr) * 1024 + a + k0 + asc];
    f32x4 a1 = *(const f32x4*)&B[(size_t)(m0 + asr) * 1024 + a + k0 + asc + 4];
    f32x4 b0 = *(const f32x4*)&M[(size_t)(a + k0 + bkr) * 1024 + n0 + bnc];
    f32x4 b1 = *(const f32x4*)&M[(size_t)(a + k0 + bkr) * 1024 + n0 + bnc + 4];
    a0 *= r2; a1 *= r2;
    __syncthreads();
#pragma unroll
    for (int q = 0; q < 4; ++q) { sA[asc + q][asr] = a0[q]; sA[asc + 4 + q][asr] = a1[q]; }
    *(f32x4*)&sB[bkr][bnc] = b0;
    *(f32x4*)&sB[bkr][bnc + 4] = b1;
    __syncthreads();
#pragma unroll
    for (int kk = 0; kk < 32; ++kk) {
      f32x4 av = *(const f32x4*)&sA[kk][ty * 4];
      f32x4 bv = *(const f32x4*)&sB[kk][tx * 4];
#pragma unroll
      for (int q = 0; q < 4; ++q) acc[q] += bv * av[q];
    }
  }
  float* up = U + (size_t)blockIdx.y * s * s;
#pragma unroll
  for (int q = 0; q < 4; ++q)
    *(f32x4*)&up[(size_t)(ti * 64 + ty * 4 + q) * s + tj * 64 + tx * 4] = acc[q];
}

// ===== level GEMM 2: M21 = -M22*U, triangular skip =====
__global__ __launch_bounds__(256) void k_moff(float* __restrict__ M, const float* __restrict__ U, int lvl) {
  __shared__ float sA[32][68];
  __shared__ float sB[32][68];
  const int tid = threadIdx.x;
  const int s = 64 << lvl;
  const int ti = blockIdx.x >> lvl, tj = blockIdx.x & ((1 << lvl) - 1);
  const int a = blockIdx.y * (s << 1);
  const int m0 = a + s + ti * 64;
  const int n0 = a + tj * 64;
  const int tx = tid & 15, ty = tid >> 4;
  const int asr = tid >> 2, asc = (tid & 3) * 8;
  const int bkr = tid >> 3, bnc = (tid & 7) * 8;
  const float* up = U + (size_t)blockIdx.y * s * s;
  const int kmax = (ti + 1) * 64;
  f32x4 acc[4];
#pragma unroll
  for (int q = 0; q < 4; ++q) acc[q] = {0.f, 0.f, 0.f, 0.f};

  for (int k0 = 0; k0 < kmax; k0 += 32) {
    f32x4 a0 = *(const f32x4*)&M[(size_t)(m0 + asr) * 1024 + a + s + k0 + asc];
    f32x4 a1 = *(const f32x4*)&M[(size_t)(m0 + asr) * 1024 + a + s + k0 + asc + 4];
    f32x4 b0 = *(const f32x4*)&up[(size_t)(k0 + bkr) * s + tj * 64 + bnc];
    f32x4 b1 = *(const f32x4*)&up[(size_t)(k0 + bkr) * s + tj * 64 + bnc + 4];
    __syncthreads();
#pragma unroll
    for (int q = 0; q < 4; ++q) { sA[asc + q][asr] = a0[q]; sA[asc + 4 + q][asr] = a1[q]; }
    *(f32x4*)&sB[bkr][bnc] = b0;
    *(f32x4*)&sB[bkr][bnc + 4] = b1;
    __syncthreads();
#pragma unroll
    for (int kk = 0; kk < 32; ++kk) {
      f32x4 av = *(const f32x4*)&sA[kk][ty * 4];
      f32x4 bv = *(const f32x4*)&sB[kk][tx * 4];
#pragma unroll
      for (int q = 0; q < 4; ++q) acc[q] += bv * av[q];
    }
  }
#pragma unroll
  for (int q = 0; q < 4; ++q)
    *(f32x4*)&M[(size_t)(m0 + ty * 4 + q) * 1024 + n0 + tx * 4] = -acc[q];
}

// ===== Y = M * A (triangular K-skip) ; + conv slice 1 =====
__global__ __launch_bounds__(256) void k_yma(const float* __restrict__ M, const float* __restrict__ A,
                                             float* __restrict__ Y,
                                             const float* __restrict__ X, u16* __restrict__ Xbf) {
  const int bid = blockIdx.x;
  const int tid = threadIdx.x;
  if (bid >= 256) { conv_slice(X, Xbf, bid - 256, 512, 4194304, 6291456); return; }
  __shared__ float sA[32][68];
  __shared__ float sB[32][68];
  const int ri = bid >> 4, cj = bid & 15;
  const int m0 = ri * 64, n0 = cj * 64;
  const int kmax = (ri + 1) * 64;
  const int tx = tid & 15, ty = tid >> 4;
  const int asr = tid >> 2, asc = (tid & 3) * 8;
  const int bkr = tid >> 3, bnc = (tid & 7) * 8;
  f32x4 acc[4];
#pragma unroll
  for (int q = 0; q < 4; ++q) acc[q] = {0.f, 0.f, 0.f, 0.f};

  for (int k0 = 0; k0 < kmax; k0 += 32) {
    f32x4 a0 = *(const f32x4*)&M[(size_t)(m0 + asr) * 1024 + k0 + asc];
    f32x4 a1 = *(const f32x4*)&M[(size_t)(m0 + asr) * 1024 + k0 + asc + 4];
    f32x4 b0 = *(const f32x4*)&A[(size_t)(k0 + bkr) * 1024 + n0 + bnc];
    f32x4 b1 = *(const f32x4*)&A[(size_t)(k0 + bkr) * 1024 + n0 + bnc + 4];
    __syncthreads();
#pragma unroll
    for (int q = 0; q < 4; ++q) { sA[asc + q][asr] = a0[q]; sA[asc + 4 + q][asr] = a1[q]; }
    *(f32x4*)&sB[bkr][bnc] = b0;
    *(f32x4*)&sB[bkr][bnc + 4] = b1;
    __syncthreads();
#pragma unroll
    for (int kk = 0; kk < 32; ++kk) {
      f32x4 av = *(const f32x4*)&sA[kk][ty * 4];
      f32x4 bv = *(const f32x4*)&sB[kk][tx * 4];
#pragma unroll
      for (int q = 0; q < 4; ++q) acc[q] += bv * av[q];
    }
  }
#pragma unroll
  for (int q = 0; q < 4; ++q)
    *(f32x4*)&Y[(size_t)(m0 + ty * 4 + q) * 1024 + n0 + tx * 4] = acc[q];
}

// ===== Wf in MFMA-B-fragment order ; + conv slice 2 =====
__global__ __launch_bounds__(256) void k_w(const float* __restrict__ A, const float* __restrict__ P,
                                           const float* __restrict__ rd2, u16* __restrict__ Wf,
                                           const float* __restrict__ X, u16* __restrict__ Xbf) {
  const int bid = blockIdx.x;
  const int tid = threadIdx.x;
  if (bid >= 256) { conv_slice(X, Xbf, bid - 256, 512, 6291456, 8388608); return; }
  __shared__ float As[32][68];
  __shared__ float Ps[32][68];
  const int kb = (bid >> 4) * 64, nb = (bid & 15) * 64;
  const int sr = tid >> 3, sc = (tid & 7) * 8;
  const int tx = tid & 15, ty = tid >> 4;
  f32x4 acc[4];
#pragma unroll
  for (int q = 0; q < 4; ++q) acc[q] = {0.f, 0.f, 0.f, 0.f};

  for (int i0 = 0; i0 < 1024; i0 += 32) {
    float r2 = rd2[i0 + sr];
    f32x4 a0 = *(const f32x4*)&A[(size_t)(i0 + sr) * 1024 + kb + sc];
    f32x4 a1 = *(const f32x4*)&A[(size_t)(i0 + sr) * 1024 + kb + sc + 4];
    f32x4 p0 = *(const f32x4*)&P[(size_t)(i0 + sr) * 1024 + nb + sc];
    f32x4 p1 = *(const f32x4*)&P[(size_t)(i0 + sr) * 1024 + nb + sc + 4];
    __syncthreads();
    *(f32x4*)&As[sr][sc]     = a0 * r2;
    *(f32x4*)&As[sr][sc + 4] = a1 * r2;
    *(f32x4*)&Ps[sr][sc]     = p0;
    *(f32x4*)&Ps[sr][sc + 4] = p1;
    __syncthreads();
#pragma unroll
    for (int i = 0; i < 32; ++i) {
      f32x4 av = *(const f32x4*)&As[i][ty * 4];
      f32x4 pv = *(const f32x4*)&Ps[i][tx * 4];
#pragma unroll
      for (int q = 0; q < 4; ++q) acc[q] += pv * av[q];
    }
  }
  const int ktile = (kb + ty * 4) >> 5;
  const int kg = ((ty * 4) >> 3) & 3;
  const int e0 = (ty * 4) & 7;
#pragma unroll
  for (int j = 0; j < 4; ++j) {
    int n = nb + tx * 4 + j;
    int nt = n >> 4;
    int ln = kg * 16 + (n & 15);
    u16x4 pk;
#pragma unroll
    for (int q = 0; q < 4; ++q) {
      int kk = kb + ty * 4 + q;
      float w = ((kk == n) ? 1.0f : 0.0f) - acc[q][j];
      pk[q] = f2bf(w);
    }
    *(u16x4*)&Wf[((size_t)(ktile * 64 + nt) * 64 + ln) * 8 + e0] = pk;
  }
}

// ===== 256x256 GEMM, 16 waves (4x4), 64x64/wave, 4 waves/SIMD, counted-vmcnt depth-3 =====
template<int I>
__device__ __forceinline__ void phase_body(const u16* __restrict__ ax, const u16* __restrict__ wbase,
                                           u16* As, u16* Bs, int tid, int wr, int wc, int lane,
                                           f32x4 (&acc)[4][4]) {
  if constexpr (I <= 29)      asm volatile("s_waitcnt vmcnt(4)" ::: "memory");
  else if constexpr (I == 30) asm volatile("s_waitcnt vmcnt(2)" ::: "memory");
  else                        asm volatile("s_waitcnt vmcnt(0)" ::: "memory");
  __builtin_amdgcn_s_barrier();   // unconditional: all waves' half-I loads landed
  if constexpr (I + 3 < 32) {     // prefetch half I+3 into slot (I+3)&3 (its reads ended phase I-1)
    constexpr int j = I + 3, js = j & 3;
    GL_LDS16(ax + (size_t)j * 8192 + tid * 8,     As + js * 8192 + tid * 8);
    GL_LDS16(wbase + (size_t)j * 32768 + tid * 8, Bs + js * 8192 + tid * 8);
  }
  const u16* Asb = As + (I & 3) * 8192;
  const u16* Bsb = Bs + (I & 3) * 8192;
  s16x8 af[4], bf[4];
#pragma unroll
  for (int m = 0; m < 4; ++m) af[m] = *(const s16x8*)&Asb[(wr * 4 + m) * 512 + lane * 8];
#pragma unroll
  for (int n = 0; n < 4; ++n) bf[n] = *(const s16x8*)&Bsb[(wc * 4 + n) * 512 + lane * 8];
  __builtin_amdgcn_s_setprio(1);
#pragma unroll
  for (int m = 0; m < 4; ++m)
#pragma unroll
    for (int n = 0; n < 4; ++n)
      acc[m][n] = __builtin_amdgcn_mfma_f32_16x16x32_bf16(af[m], bf[n], acc[m][n], 0, 0, 0);
  __builtin_amdgcn_s_setprio(0);
}

__global__ __launch_bounds__(1024, 4) void k_out8(const u16* __restrict__ Xbf, const u16* __restrict__ Wf,
                                                  const float* __restrict__ bvec, float* __restrict__ out) {
  __shared__ u16 As[32768];   // 4 slots x 16KB (A half: 256 rows x 32 k bf16)
  __shared__ u16 Bs[32768];   // 4 slots x 16KB (B half)
  const int tid = threadIdx.x;
  const int lane = tid & 63, wid = tid >> 6;
  const int wr = wid >> 2, wc = wid & 3;          // 4M x 4N waves; per-wave out 64x64
  const int lin = blockIdx.x;
  const int xcd = lin & 7, idx = lin >> 3;
  const int mi = xcd * 32 + (idx >> 2);           // XCD-chunked
  const int ni = idx & 3;

  const u16* ax = Xbf + (size_t)mi * 262144;      // per half: 8192 u16 (16KB)
  const u16* wbase = Wf + (size_t)ni * 8192;      // per half: +32768 u16

  f32x4 acc[4][4];
#pragma unroll
  for (int m = 0; m < 4; ++m)
#pragma unroll
    for (int n = 0; n < 4; ++n) acc[m][n] = {0.f, 0.f, 0.f, 0.f};

  // prologue: issue halves 0,1,2 (A+B each, 1 load/thread each)
#pragma unroll
  for (int j = 0; j < 3; ++j) {
    GL_LDS16(ax + (size_t)j * 8192 + tid * 8,     As + j * 8192 + tid * 8);
    GL_LDS16(wbase + (size_t)j * 32768 + tid * 8, Bs + j * 8192 + tid * 8);
  }

#define PH(I) phase_body<I>(ax, wbase, As, Bs, tid, wr, wc, lane, acc);
  PH(0)  PH(1)  PH(2)  PH(3)  PH(4)  PH(5)  PH(6)  PH(7)
  PH(8)  PH(9)  PH(10) PH(11) PH(12) PH(13) PH(14) PH(15)
  PH(16) PH(17) PH(18) PH(19) PH(20) PH(21) PH(22) PH(23)
  PH(24) PH(25) PH(26) PH(27) PH(28) PH(29) PH(30) PH(31)
#undef PH

  const long orow0 = (long)mi * 256 + wr * 64 + (lane >> 4) * 4;
  const int  ocol0 = ni * 256 + wc * 64 + (lane & 15);
#pragma unroll
  for (int aj = 0; aj < 4; ++aj) {
    const int cc = ocol0 + aj * 16;
    const float bb = bvec[cc];
#pragma unroll
    for (int ai = 0; ai < 4; ++ai) {
      const long r = orow0 + ai * 16;
#pragma unroll
      for (int q = 0; q < 4; ++q)
        out[(r + q) * 1024 + cc] = acc[ai][aj][q] + bb;
    }
  }
}

// ===== fallback GEMM (reg-staged A) if workspace too small for Xbf =====
__global__ __launch_bounds__(256) void k_out_r(const float* __restrict__ X, const u16* __restrict__ Wf,
                                               const float* __restrict__ bvec, float* __restrict__ out) {
  __shared__ u16 As[8192];
  __shared__ u16 Bs[8192];
  const int tid = threadIdx.x;
  const int lane = tid & 63, wid = tid >> 6;
  const int wr = wid >> 1, wc = wid & 1;
  const int lin = blockIdx.x;
  const int mi = (lin & 7) * 64 + (lin >> 6);
  const int ni = (lin >> 3) & 7;
  const long m0 = (long)mi * 128;
  const int n0 = ni * 128;

  const float *xs0, *xs1, *xs2, *xs3;
  int aw0, aw1, aw2, aw3;
#define APREP(J, XS, AW) { int c = (J) * 256 + tid; int m = c >> 3, kg8 = c & 7;       \
    XS = X + (m0 + m) * 1024 + kg8 * 8;                                                \
    int kt2 = kg8 >> 2, ks = kg8 & 3, msub = m >> 4, mm = m & 15;                      \
    AW = (((kt2 * 8 + msub) * 64 + ks * 16 + mm) * 16) ^ (ks << 4); }
  APREP(0, xs0, aw0) APREP(1, xs1, aw1) APREP(2, xs2, aw2) APREP(3, xs3, aw3)
#undef APREP

  const u16* wsrc0 = Wf + (size_t)ni * 4096 + tid * 8;
  u16* bd0 = Bs + tid * 8;
  const int aro = (lane * 16) ^ (((lane >> 4) & 3) << 4);
  const char* Ab = (const char*)As + aro;
  const char* Bb = (const char*)Bs + lane * 16;

  f32x4 acc[4][4];
#pragma unroll
  for (int m = 0; m < 4; ++m)
#pragma unroll
    for (int n = 0; n < 4; ++n) acc[m][n] = {0.f, 0.f, 0.f, 0.f};

  for (int it = 0; it < 16; ++it) {
    const u16* w0 = wsrc0 + (size_t)it * 65536;
    GL_LDS16(w0,          bd0);
    GL_LDS16(w0 + 2048,   bd0 + 2048);
    GL_LDS16(w0 + 32768,  bd0 + 4096);
    GL_LDS16(w0 + 34816,  bd0 + 6144);
    const int ko = it * 64;
#define ASTAGE(XS, AW) { f32x4 u = *(const f32x4*)((XS) + ko); f32x4 v = *(const f32x4*)((XS) + ko + 4); \
    u16x8 h;                                                                              \
    h[0] = cvtbf(u[0]); h[1] = cvtbf(u[1]); h[2] = cvtbf(u[2]); h[3] = cvtbf(u[3]);       \
    h[4] = cvtbf(v[0]); h[5] = cvtbf(v[1]); h[6] = cvtbf(v[2]); h[7] = cvtbf(v[3]);       \
    *(u16x8*)((char*)As + (AW)) = h; }
    ASTAGE(xs0, aw0) ASTAGE(xs1, aw1) ASTAGE(xs2, aw2) ASTAGE(xs3, aw3)
#undef ASTAGE
    __syncthreads();
#pragma unroll
    for (int kt2 = 0; kt2 < 2; ++kt2) {
      s16x8 af[4], bfr[4];
#pragma unroll
      for (int m = 0; m < 4; ++m) af[m] = *(const s16x8*)(Ab + ((kt2 * 8 + wr * 4 + m) << 10));
#pragma unroll
      for (int n = 0; n < 4; ++n) bfr[n] = *(const s16x8*)(Bb + ((kt2 * 8 + wc * 4 + n) << 10));
#pragma unroll
      for (int m = 0; m < 4; ++m)
#pragma unroll
        for (int n = 0; n < 4; ++n)
          acc[m][n] = __builtin_amdgcn_mfma_f32_16x16x32_bf16(af[m], bfr[n], acc[m][n], 0, 0, 0);
    }
    __syncthreads();
  }

  const long orow0 = m0 + wr * 64 + (lane >> 4) * 4;
  const int  ocol0 = n0 + wc * 64 + (lane & 15);
#pragma unroll
  for (int n = 0; n < 4; ++n) {
    const int cc = ocol0 + n * 16;
    const float bb = bvec[cc];
#pragma unroll
    for (int m = 0; m < 4; ++m) {
      const long r = orow0 + m * 16;
#pragma unroll
      for (int q = 0; q < 4; ++q)
        out[(r + q) * 1024 + cc] = acc[m][n][q] + bb;
    }
  }
}

extern "C" void kernel_launch(void* const* d_in, const int* in_sizes, int n_in,
                              void* d_out, int out_size, void* d_ws, size_t ws_size,
                              hipStream_t stream) {
  const float* x  = (const float*)d_in[0];
  const float* A  = (const float*)d_in[1];
  const float* bv = (const float*)d_in[2];
  float* out = (float*)d_out;
  char* ws = (char*)d_ws;

  float* B   = (float*)(ws);                              // 4 MB, becomes Y
  float* Y   = B;
  float* M   = (float*)(ws + (4u << 20));                 // 4 MB
  u16*   Wf  = (u16*)  (ws + (8u << 20));                 // 2 MB
  float* rd2 = (float*)(ws + (10u << 20));                // 4 KB
  float* U   = (float*)(ws + (10u << 20) + 65536);        // 1 MB
  u16*   Xbf = (u16*)  (ws + (12u << 20));                // 128 MB

  const size_t need = (12u << 20) + (size_t)65536 * 1024 * 2;
  const bool big = (ws_size >= need);

  k_bbtx<<<big ? 1160 : 136, 256, 0, stream>>>(A, B, rd2, M, x, Xbf);
  k_lvl0<<<8, 256, 0, stream>>>(B, rd2, M);
  for (int lvl = 1; lvl < 4; ++lvl) {
    const int nt2 = 1 << (2 * lvl);
    const int np  = 8 >> lvl;
    k_u<<<dim3(nt2, np), 256, 0, stream>>>(B, rd2, M, U, lvl);
    k_moff<<<dim3(nt2, np), 256, 0, stream>>>(M, U, lvl);
  }
  k_yma<<<big ? 768 : 256, 256, 0, stream>>>(M, A, Y, x, Xbf);
  k_w<<<big ? 768 : 256, 256, 0, stream>>>(A, Y, rd2, Wf, x, Xbf);

  if (big) {
    k_out8<<<1024, 1024, 0, stream>>>(Xbf, Wf, bv, out);
  } else {
    k_out_r<<<4096, 256, 0, stream>>>(x, Wf, bv, out);
  }
}

// Round 13
// 456.442 us; speedup vs baseline: 1.4337x; 1.0423x over previous
//
#include <hip/hip_runtime.h>
#include <hip/hip_bf16.h>

typedef unsigned short u16;
typedef float f32x4 __attribute__((ext_vector_type(4)));
typedef u16   u16x8 __attribute__((ext_vector_type(8)));
typedef u16   u16x4 __attribute__((ext_vector_type(4)));
typedef short s16x8 __attribute__((ext_vector_type(8)));

__device__ __forceinline__ u16 f2bf(float f) {
  unsigned u = __builtin_bit_cast(unsigned, f);
  unsigned r = (u + 0x7fffu + ((u >> 16) & 1u)) >> 16;
  return (u16)r;
}
__device__ __forceinline__ u16 cvtbf(float f) {
  return __builtin_bit_cast(u16, __float2bfloat16(f));
}

#define GL_LDS16(gp, lp)                                                     \
  __builtin_amdgcn_global_load_lds((const __attribute__((address_space(1))) void*)(gp), \
                                   (__attribute__((address_space(3))) void*)(lp), 16, 0, 0)

// ---- X fp32 -> bf16 slice converter (A-fragment order: [mi256][half(32)][msub(16)][lane(64)][8]) ----
__device__ __forceinline__ void conv_slice(const float* __restrict__ X, u16* __restrict__ Xbf,
                                           int cb, int nblocks, int lo, int hi) {
  for (int gid = lo + cb * 256 + (int)threadIdx.x; gid < hi; gid += nblocks * 256) {
    const int mi   = gid >> 15;
    const int half = (gid >> 10) & 31;
    const int msub = (gid >> 6) & 15;
    const int lane = gid & 63;
    const int m = mi * 256 + msub * 16 + (lane & 15);
    const int k = half * 32 + (lane >> 4) * 8;
    const float* s = X + (size_t)m * 1024 + k;
    f32x4 u = *(const f32x4*)s;
    f32x4 v = *(const f32x4*)(s + 4);
    u16x8 h;
    h[0] = cvtbf(u[0]); h[1] = cvtbf(u[1]); h[2] = cvtbf(u[2]); h[3] = cvtbf(u[3]);
    h[4] = cvtbf(v[0]); h[5] = cvtbf(v[1]); h[6] = cvtbf(v[2]); h[7] = cvtbf(v[3]);
    *(u16x8*)(Xbf + (size_t)gid * 8) = h;
  }
}

// ===== K1: B=A*A^T (136 sym tiles, mirrored, rotated pipeline) + rd2 + diag inverses + conv =====
__global__ __launch_bounds__(256) void k_bbtx(const float* __restrict__ A, float* __restrict__ B,
                                              float* __restrict__ rd2, float* __restrict__ M,
                                              const float* __restrict__ X, u16* __restrict__ Xbf) {
  const int bid = blockIdx.x;
  const int tid = threadIdx.x;
  if (bid >= 136) { conv_slice(X, Xbf, bid - 136, 1024, 0, 4194304); return; }

  __shared__ float s0[32][68];
  __shared__ float s1[32][68];
  __shared__ float Ct[64][68];
  __shared__ float rdl[64];

  int t = bid, ii = 0;
  while (t >= 16 - ii) { t -= 16 - ii; ++ii; }
  const int jj = ii + t;
  const int i0 = ii * 64, j0 = jj * 64;
  const int tx = tid & 15, ty = tid >> 4;
  const int sr = tid >> 2, sc = (tid & 3) * 8;
  f32x4 acc[4];
#pragma unroll
  for (int q = 0; q < 4; ++q) acc[q] = {0.f, 0.f, 0.f, 0.f};

  const float* pa = &A[(size_t)(i0 + sr) * 1024 + sc];
  const float* pb = &A[(size_t)(j0 + sr) * 1024 + sc];
  // rotated pipeline: regs hold slab k0; loads for k0+32 issue BEFORE compute of k0
  f32x4 ra0 = *(const f32x4*)(pa);
  f32x4 ra1 = *(const f32x4*)(pa + 4);
  f32x4 rb0 = *(const f32x4*)(pb);
  f32x4 rb1 = *(const f32x4*)(pb + 4);

  for (int k0 = 0; k0 < 1024; k0 += 32) {
    __syncthreads();                      // prior compute's LDS reads done
#pragma unroll
    for (int q = 0; q < 4; ++q) {
      s0[sc + q][sr] = ra0[q]; s0[sc + 4 + q][sr] = ra1[q];
      s1[sc + q][sr] = rb0[q]; s1[sc + 4 + q][sr] = rb1[q];
    }
    __syncthreads();                      // writes visible
    if (k0 < 992) {                       // issue next slab now; completes under compute
      ra0 = *(const f32x4*)(pa + k0 + 32);
      ra1 = *(const f32x4*)(pa + k0 + 36);
      rb0 = *(const f32x4*)(pb + k0 + 32);
      rb1 = *(const f32x4*)(pb + k0 + 36);
    }
#pragma unroll
    for (int kk = 0; kk < 32; ++kk) {
      f32x4 av = *(const f32x4*)&s0[kk][ty * 4];
      f32x4 bv = *(const f32x4*)&s1[kk][tx * 4];
#pragma unroll
      for (int q = 0; q < 4; ++q) acc[q] += bv * av[q];
    }
  }
#pragma unroll
  for (int q = 0; q < 4; ++q)
    *(f32x4*)&B[(size_t)(i0 + ty * 4 + q) * 1024 + j0 + tx * 4] = acc[q];

  if (ii != jj) {
#pragma unroll
    for (int q = 0; q < 4; ++q)
#pragma unroll
      for (int w = 0; w < 4; ++w)
        B[(size_t)(j0 + tx * 4 + w) * 1024 + i0 + ty * 4 + q] = acc[q][w];
    return;
  }
  // diagonal block: rd2 + 64x64 inverse T = (I+L)^-1 -> M diagonal
  if (tx == ty) {
#pragma unroll
    for (int q = 0; q < 4; ++q) {
      float v = 2.0f / acc[q][q];
      rdl[ty * 4 + q] = v;
      rd2[i0 + ty * 4 + q] = v;
    }
  }
  __syncthreads();
#pragma unroll
  for (int q = 0; q < 4; ++q)
#pragma unroll
    for (int j = 0; j < 4; ++j) {
      int r = ty * 4 + q, c = tx * 4 + j;
      Ct[r][c] = (c > r) ? acc[q][j] * rdl[c] : 0.0f;
    }
  __syncthreads();
  if (tid < 64) {
    float pc[64];
#pragma unroll
    for (int r = 0; r < 64; ++r) pc[r] = (r == tid) ? 1.0f : 0.0f;
#pragma unroll
    for (int i = 0; i < 63; ++i) {
      const float pi = pc[i];
#pragma unroll
      for (int j = i + 1; j < 64; ++j) pc[j] -= Ct[i][j] * pi;
    }
#pragma unroll
    for (int r = 0; r < 64; ++r) M[(size_t)(i0 + r) * 1024 + i0 + tid] = pc[r];
  }
}

// ===== level 0 fused: per pair p, U = Cs*M11 (LDS), then M21 = -M22*U =====
__global__ __launch_bounds__(256) void k_lvl0(const float* __restrict__ B, const float* __restrict__ rd2,
                                              float* __restrict__ M) {
  __shared__ float sA[32][68];
  __shared__ float sB[32][68];
  __shared__ float Us[64][68];
  const int tid = threadIdx.x;
  const int a = blockIdx.x * 128;
  const int m0 = a + 64;
  const int tx = tid & 15, ty = tid >> 4;
  const int asr = tid >> 2, asc = (tid & 3) * 8;
  const int bkr = tid >> 3, bnc = (tid & 7) * 8;
  const float r2 = rd2[m0 + asr];
  f32x4 acc[4];
#pragma unroll
  for (int q = 0; q < 4; ++q) acc[q] = {0.f, 0.f, 0.f, 0.f};
  for (int k0 = 0; k0 < 64; k0 += 32) {
    f32x4 a0 = *(const f32x4*)&B[(size_t)(m0 + asr) * 1024 + a + k0 + asc];
    f32x4 a1 = *(const f32x4*)&B[(size_t)(m0 + asr) * 1024 + a + k0 + asc + 4];
    f32x4 b0 = *(const f32x4*)&M[(size_t)(a + k0 + bkr) * 1024 + a + bnc];
    f32x4 b1 = *(const f32x4*)&M[(size_t)(a + k0 + bkr) * 1024 + a + bnc + 4];
    a0 *= r2; a1 *= r2;
    __syncthreads();
#pragma unroll
    for (int q = 0; q < 4; ++q) { sA[asc + q][asr] = a0[q]; sA[asc + 4 + q][asr] = a1[q]; }
    *(f32x4*)&sB[bkr][bnc] = b0;
    *(f32x4*)&sB[bkr][bnc + 4] = b1;
    __syncthreads();
#pragma unroll
    for (int kk = 0; kk < 32; ++kk) {
      f32x4 av = *(const f32x4*)&sA[kk][ty * 4];
      f32x4 bv = *(const f32x4*)&sB[kk][tx * 4];
#pragma unroll
      for (int q = 0; q < 4; ++q) acc[q] += bv * av[q];
    }
  }
#pragma unroll
  for (int q = 0; q < 4; ++q) *(f32x4*)&Us[ty * 4 + q][tx * 4] = acc[q];
#pragma unroll
  for (int q = 0; q < 4; ++q) acc[q] = {0.f, 0.f, 0.f, 0.f};
  for (int k0 = 0; k0 < 64; k0 += 32) {
    f32x4 a0 = *(const f32x4*)&M[(size_t)(m0 + asr) * 1024 + m0 + k0 + asc];
    f32x4 a1 = *(const f32x4*)&M[(size_t)(m0 + asr) * 1024 + m0 + k0 + asc + 4];
    __syncthreads();   // also publishes Us writes on first iteration
#pragma unroll
    for (int q = 0; q < 4; ++q) { sA[asc + q][asr] = a0[q]; sA[asc + 4 + q][asr] = a1[q]; }
    __syncthreads();
#pragma unroll
    for (int kk = 0; kk < 32; ++kk) {
      f32x4 av = *(const f32x4*)&sA[kk][ty * 4];
      f32x4 bv = *(const f32x4*)&Us[k0 + kk][tx * 4];
#pragma unroll
      for (int q = 0; q < 4; ++q) acc[q] += bv * av[q];
    }
  }
#pragma unroll
  for (int q = 0; q < 4; ++q)
    *(f32x4*)&M[(size_t)(m0 + ty * 4 + q) * 1024 + a + tx * 4] = -acc[q];
}

// ===== level GEMM 1 (lvl>=1): U_p = Cscaled * M11, triangular skip =====
__global__ __launch_bounds__(256) void k_u(const float* __restrict__ B, const float* __restrict__ rd2,
                                           const float* __restrict__ M, float* __restrict__ U, int lvl) {
  __shared__ float sA[32][68];
  __shared__ float sB[32][68];
  const int tid = threadIdx.x;
  const int s = 64 << lvl;
  const int ti = blockIdx.x >> lvl, tj = blockIdx.x & ((1 << lvl) - 1);
  const int a = blockIdx.y * (s << 1);
  const int m0 = a + s + ti * 64;
  const int n0 = a + tj * 64;
  const int tx = tid & 15, ty = tid >> 4;
  const int asr = tid >> 2, asc = (tid & 3) * 8;
  const int bkr = tid >> 3, bnc = (tid & 7) * 8;
  const float r2 = rd2[m0 + asr];
  f32x4 acc[4];
#pragma unroll
  for (int q = 0; q < 4; ++q) acc[q] = {0.f, 0.f, 0.f, 0.f};

  for (int k0 = tj * 64; k0 < s; k0 += 32) {
    f32x4 a0 = *(const f32x4*)&B[(size_t)(m0 + asr) * 1024 + a + k0 + asc];
    f32x4 a1 = *(const f32x4*)&B[(size_t)(m0 + asr) * 1024 + a + k0 + asc + 4];
    f32x4 b0 = *(const f32x4*)&M[(size_t)(a + k0 + bkr) * 1024 + n0 + bnc];
    f32x4 b1 = *(const f32x4*)&M[(size_t)(a + k0 + bkr) * 1024 + n0 + bnc + 4];
    a0 *= r2; a1 *= r2;
    __syncthreads();
#pragma unroll
    for (int q = 0; q < 4; ++q) { sA[asc + q][asr] = a0[q]; sA[asc + 4 + q][asr] = a1[q]; }
    *(f32x4*)&sB[bkr][bnc] = b0;
    *(f32x4*)&sB[bkr][bnc + 4] = b1;
    __syncthreads();
#pragma unroll
    for (int kk = 0; kk < 32; ++kk) {
      f32x4 av = *(const f32x4*)&sA[kk][ty * 4];
      f32x4 bv = *(const f32x4*)&sB[kk][tx * 4];
#pragma unroll
      for (int q = 0; q < 4; ++q) acc[q] += bv * av[q];
    }
  }
  float* up = U + (size_t)blockIdx.y * s * s;
#pragma unroll
  for (int q = 0; q < 4; ++q)
    *(f32x4*)&up[(size_t)(ti * 64 + ty * 4 + q) * s + tj * 64 + tx * 4] = acc[q];
}

// ===== level GEMM 2: M21 = -M22*U, triangular skip =====
__global__ __launch_bounds__(256) void k_moff(float* __restrict__ M, const float* __restrict__ U, int lvl) {
  __shared__ float sA[32][68];
  __shared__ float sB[32][68];
  const int tid = threadIdx.x;
  const int s = 64 << lvl;
  const int ti = blockIdx.x >> lvl, tj = blockIdx.x & ((1 << lvl) - 1);
  const int a = blockIdx.y * (s << 1);
  const int m0 = a + s + ti * 64;
  const int n0 = a + tj * 64;
  const int tx = tid & 15, ty = tid >> 4;
  const int asr = tid >> 2, asc = (tid & 3) * 8;
  const int bkr = tid >> 3, bnc = (tid & 7) * 8;
  const float* up = U + (size_t)blockIdx.y * s * s;
  const int kmax = (ti + 1) * 64;
  f32x4 acc[4];
#pragma unroll
  for (int q = 0; q < 4; ++q) acc[q] = {0.f, 0.f, 0.f, 0.f};

  for (int k0 = 0; k0 < kmax; k0 += 32) {
    f32x4 a0 = *(const f32x4*)&M[(size_t)(m0 + asr) * 1024 + a + s + k0 + asc];
    f32x4 a1 = *(const f32x4*)&M[(size_t)(m0 + asr) * 1024 + a + s + k0 + asc + 4];
    f32x4 b0 = *(const f32x4*)&up[(size_t)(k0 + bkr) * s + tj * 64 + bnc];
    f32x4 b1 = *(const f32x4*)&up[(size_t)(k0 + bkr) * s + tj * 64 + bnc + 4];
    __syncthreads();
#pragma unroll
    for (int q = 0; q < 4; ++q) { sA[asc + q][asr] = a0[q]; sA[asc + 4 + q][asr] = a1[q]; }
    *(f32x4*)&sB[bkr][bnc] = b0;
    *(f32x4*)&sB[bkr][bnc + 4] = b1;
    __syncthreads();
#pragma unroll
    for (int kk = 0; kk < 32; ++kk) {
      f32x4 av = *(const f32x4*)&sA[kk][ty * 4];
      f32x4 bv = *(const f32x4*)&sB[kk][tx * 4];
#pragma unroll
      for (int q = 0; q < 4; ++q) acc[q] += bv * av[q];
    }
  }
#pragma unroll
  for (int q = 0; q < 4; ++q)
    *(f32x4*)&M[(size_t)(m0 + ty * 4 + q) * 1024 + n0 + tx * 4] = -acc[q];
}

// ===== Y = M * A (triangular K-skip, rotated pipeline) ; + conv slice 1 =====
__global__ __launch_bounds__(256) void k_yma(const float* __restrict__ M, const float* __restrict__ A,
                                             float* __restrict__ Y,
                                             const float* __restrict__ X, u16* __restrict__ Xbf) {
  const int bid = blockIdx.x;
  const int tid = threadIdx.x;
  if (bid >= 256) { conv_slice(X, Xbf, bid - 256, 512, 4194304, 6291456); return; }
  __shared__ float sA[32][68];
  __shared__ float sB[32][68];
  const int ri = bid >> 4, cj = bid & 15;
  const int m0 = ri * 64, n0 = cj * 64;
  const int kmax = (ri + 1) * 64;
  const int tx = tid & 15, ty = tid >> 4;
  const int asr = tid >> 2, asc = (tid & 3) * 8;
  const int bkr = tid >> 3, bnc = (tid & 7) * 8;
  f32x4 acc[4];
#pragma unroll
  for (int q = 0; q < 4; ++q) acc[q] = {0.f, 0.f, 0.f, 0.f};

  const float* pm = &M[(size_t)(m0 + asr) * 1024 + asc];
  f32x4 ra0 = *(const f32x4*)(pm);
  f32x4 ra1 = *(const f32x4*)(pm + 4);
  f32x4 rb0 = *(const f32x4*)&A[(size_t)bkr * 1024 + n0 + bnc];
  f32x4 rb1 = *(const f32x4*)&A[(size_t)bkr * 1024 + n0 + bnc + 4];

  for (int k0 = 0; k0 < kmax; k0 += 32) {
    __syncthreads();
#pragma unroll
    for (int q = 0; q < 4; ++q) { sA[asc + q][asr] = ra0[q]; sA[asc + 4 + q][asr] = ra1[q]; }
    *(f32x4*)&sB[bkr][bnc] = rb0;
    *(f32x4*)&sB[bkr][bnc + 4] = rb1;
    __syncthreads();
    if (k0 + 32 < kmax) {
      ra0 = *(const f32x4*)(pm + k0 + 32);
      ra1 = *(const f32x4*)(pm + k0 + 36);
      rb0 = *(const f32x4*)&A[(size_t)(k0 + 32 + bkr) * 1024 + n0 + bnc];
      rb1 = *(const f32x4*)&A[(size_t)(k0 + 32 + bkr) * 1024 + n0 + bnc + 4];
    }
#pragma unroll
    for (int kk = 0; kk < 32; ++kk) {
      f32x4 av = *(const f32x4*)&sA[kk][ty * 4];
      f32x4 bv = *(const f32x4*)&sB[kk][tx * 4];
#pragma unroll
      for (int q = 0; q < 4; ++q) acc[q] += bv * av[q];
    }
  }
#pragma unroll
  for (int q = 0; q < 4; ++q)
    *(f32x4*)&Y[(size_t)(m0 + ty * 4 + q) * 1024 + n0 + tx * 4] = acc[q];
}

// ===== Wf in MFMA-B-fragment order (rotated pipeline) ; + conv slice 2 =====
__global__ __launch_bounds__(256) void k_w(const float* __restrict__ A, const float* __restrict__ P,
                                           const float* __restrict__ rd2, u16* __restrict__ Wf,
                                           const float* __restrict__ X, u16* __restrict__ Xbf) {
  const int bid = blockIdx.x;
  const int tid = threadIdx.x;
  if (bid >= 256) { conv_slice(X, Xbf, bid - 256, 512, 6291456, 8388608); return; }
  __shared__ float As[32][68];
  __shared__ float Ps[32][68];
  const int kb = (bid >> 4) * 64, nb = (bid & 15) * 64;
  const int sr = tid >> 3, sc = (tid & 7) * 8;
  const int tx = tid & 15, ty = tid >> 4;
  f32x4 acc[4];
#pragma unroll
  for (int q = 0; q < 4; ++q) acc[q] = {0.f, 0.f, 0.f, 0.f};

  const float* pa = &A[(size_t)sr * 1024 + kb + sc];
  const float* pp = &P[(size_t)sr * 1024 + nb + sc];
  float rr2 = rd2[sr];
  f32x4 ra0 = *(const f32x4*)(pa);
  f32x4 ra1 = *(const f32x4*)(pa + 4);
  f32x4 rp0 = *(const f32x4*)(pp);
  f32x4 rp1 = *(const f32x4*)(pp + 4);

  for (int i0 = 0; i0 < 1024; i0 += 32) {
    __syncthreads();
    *(f32x4*)&As[sr][sc]     = ra0 * rr2;
    *(f32x4*)&As[sr][sc + 4] = ra1 * rr2;
    *(f32x4*)&Ps[sr][sc]     = rp0;
    *(f32x4*)&Ps[sr][sc + 4] = rp1;
    __syncthreads();
    if (i0 < 992) {
      const size_t off = (size_t)(i0 + 32) * 1024;
      ra0 = *(const f32x4*)(pa + off);
      ra1 = *(const f32x4*)(pa + off + 4);
      rp0 = *(const f32x4*)(pp + off);
      rp1 = *(const f32x4*)(pp + off + 4);
      rr2 = rd2[i0 + 32 + sr];
    }
#pragma unroll
    for (int i = 0; i < 32; ++i) {
      f32x4 av = *(const f32x4*)&As[i][ty * 4];
      f32x4 pv = *(const f32x4*)&Ps[i][tx * 4];
#pragma unroll
      for (int q = 0; q < 4; ++q) acc[q] += pv * av[q];
    }
  }
  const int ktile = (kb + ty * 4) >> 5;
  const int kg = ((ty * 4) >> 3) & 3;
  const int e0 = (ty * 4) & 7;
#pragma unroll
  for (int j = 0; j < 4; ++j) {
    int n = nb + tx * 4 + j;
    int nt = n >> 4;
    int ln = kg * 16 + (n & 15);
    u16x4 pk;
#pragma unroll
    for (int q = 0; q < 4; ++q) {
      int kk = kb + ty * 4 + q;
      float w = ((kk == n) ? 1.0f : 0.0f) - acc[q][j];
      pk[q] = f2bf(w);
    }
    *(u16x4*)&Wf[((size_t)(ktile * 64 + nt) * 64 + ln) * 8 + e0] = pk;
  }
}

// ===== 256x256 GEMM, 16 waves (4x4), 64x64/wave, 4 waves/SIMD, counted-vmcnt depth-3 =====
template<int I>
__device__ __forceinline__ void phase_body(const u16* __restrict__ ax, const u16* __restrict__ wbase,
                                           u16* As, u16* Bs, int tid, int wr, int wc, int lane,
                                           f32x4 (&acc)[4][4]) {
  if constexpr (I <= 29)      asm volatile("s_waitcnt vmcnt(4)" ::: "memory");
  else if constexpr (I == 30) asm volatile("s_waitcnt vmcnt(2)" ::: "memory");
  else                        asm volatile("s_waitcnt vmcnt(0)" ::: "memory");
  __builtin_amdgcn_s_barrier();   // unconditional: all waves' half-I loads landed
  if constexpr (I + 3 < 32) {     // prefetch half I+3 into slot (I+3)&3 (its reads ended phase I-1)
    constexpr int j = I + 3, js = j & 3;
    GL_LDS16(ax + (size_t)j * 8192 + tid * 8,     As + js * 8192 + tid * 8);
    GL_LDS16(wbase + (size_t)j * 32768 + tid * 8, Bs + js * 8192 + tid * 8);
  }
  const u16* Asb = As + (I & 3) * 8192;
  const u16* Bsb = Bs + (I & 3) * 8192;
  s16x8 af[4], bf[4];
#pragma unroll
  for (int m = 0; m < 4; ++m) af[m] = *(const s16x8*)&Asb[(wr * 4 + m) * 512 + lane * 8];
#pragma unroll
  for (int n = 0; n < 4; ++n) bf[n] = *(const s16x8*)&Bsb[(wc * 4 + n) * 512 + lane * 8];
  __builtin_amdgcn_s_setprio(1);
#pragma unroll
  for (int m = 0; m < 4; ++m)
#pragma unroll
    for (int n = 0; n < 4; ++n)
      acc[m][n] = __builtin_amdgcn_mfma_f32_16x16x32_bf16(af[m], bf[n], acc[m][n], 0, 0, 0);
  __builtin_amdgcn_s_setprio(0);
}

__global__ __launch_bounds__(1024, 4) void k_out8(const u16* __restrict__ Xbf, const u16* __restrict__ Wf,
                                                  const float* __restrict__ bvec, float* __restrict__ out) {
  __shared__ u16 As[32768];   // 4 slots x 16KB (A half: 256 rows x 32 k bf16)
  __shared__ u16 Bs[32768];   // 4 slots x 16KB (B half)
  const int tid = threadIdx.x;
  const int lane = tid & 63, wid = tid >> 6;
  const int wr = wid >> 2, wc = wid & 3;          // 4M x 4N waves; per-wave out 64x64
  const int lin = blockIdx.x;
  const int xcd = lin & 7, idx = lin >> 3;
  const int mi = xcd * 32 + (idx >> 2);           // XCD-chunked
  const int ni = idx & 3;

  const u16* ax = Xbf + (size_t)mi * 262144;      // per half: 8192 u16 (16KB)
  const u16* wbase = Wf + (size_t)ni * 8192;      // per half: +32768 u16

  f32x4 acc[4][4];
#pragma unroll
  for (int m = 0; m < 4; ++m)
#pragma unroll
    for (int n = 0; n < 4; ++n) acc[m][n] = {0.f, 0.f, 0.f, 0.f};

  // prologue: issue halves 0,1,2 (A+B each, 1 load/thread each)
#pragma unroll
  for (int j = 0; j < 3; ++j) {
    GL_LDS16(ax + (size_t)j * 8192 + tid * 8,     As + j * 8192 + tid * 8);
    GL_LDS16(wbase + (size_t)j * 32768 + tid * 8, Bs + j * 8192 + tid * 8);
  }

#define PH(I) phase_body<I>(ax, wbase, As, Bs, tid, wr, wc, lane, acc);
  PH(0)  PH(1)  PH(2)  PH(3)  PH(4)  PH(5)  PH(6)  PH(7)
  PH(8)  PH(9)  PH(10) PH(11) PH(12) PH(13) PH(14) PH(15)
  PH(16) PH(17) PH(18) PH(19) PH(20) PH(21) PH(22) PH(23)
  PH(24) PH(25) PH(26) PH(27) PH(28) PH(29) PH(30) PH(31)
#undef PH

  const long orow0 = (long)mi * 256 + wr * 64 + (lane >> 4) * 4;
  const int  ocol0 = ni * 256 + wc * 64 + (lane & 15);
#pragma unroll
  for (int aj = 0; aj < 4; ++aj) {
    const int cc = ocol0 + aj * 16;
    const float bb = bvec[cc];
#pragma unroll
    for (int ai = 0; ai < 4; ++ai) {
      const long r = orow0 + ai * 16;
#pragma unroll
      for (int q = 0; q < 4; ++q)
        out[(r + q) * 1024 + cc] = acc[ai][aj][q] + bb;
    }
  }
}

// ===== fallback GEMM (reg-staged A) if workspace too small for Xbf =====
__global__ __launch_bounds__(256) void k_out_r(const float* __restrict__ X, const u16* __restrict__ Wf,
                                               const float* __restrict__ bvec, float* __restrict__ out) {
  __shared__ u16 As[8192];
  __shared__ u16 Bs[8192];
  const int tid = threadIdx.x;
  const int lane = tid & 63, wid = tid >> 6;
  const int wr = wid >> 1, wc = wid & 1;
  const int lin = blockIdx.x;
  const int mi = (lin & 7) * 64 + (lin >> 6);
  const int ni = (lin >> 3) & 7;
  const long m0 = (long)mi * 128;
  const int n0 = ni * 128;

  const float *xs0, *xs1, *xs2, *xs3;
  int aw0, aw1, aw2, aw3;
#define APREP(J, XS, AW) { int c = (J) * 256 + tid; int m = c >> 3, kg8 = c & 7;       \
    XS = X + (m0 + m) * 1024 + kg8 * 8;                                                \
    int kt2 = kg8 >> 2, ks = kg8 & 3, msub = m >> 4, mm = m & 15;                      \
    AW = (((kt2 * 8 + msub) * 64 + ks * 16 + mm) * 16) ^ (ks << 4); }
  APREP(0, xs0, aw0) APREP(1, xs1, aw1) APREP(2, xs2, aw2) APREP(3, xs3, aw3)
#undef APREP

  const u16* wsrc0 = Wf + (size_t)ni * 4096 + tid * 8;
  u16* bd0 = Bs + tid * 8;
  const int aro = (lane * 16) ^ (((lane >> 4) & 3) << 4);
  const char* Ab = (const char*)As + aro;
  const char* Bb = (const char*)Bs + lane * 16;

  f32x4 acc[4][4];
#pragma unroll
  for (int m = 0; m < 4; ++m)
#pragma unroll
    for (int n = 0; n < 4; ++n) acc[m][n] = {0.f, 0.f, 0.f, 0.f};

  for (int it = 0; it < 16; ++it) {
    const u16* w0 = wsrc0 + (size_t)it * 65536;
    GL_LDS16(w0,          bd0);
    GL_LDS16(w0 + 2048,   bd0 + 2048);
    GL_LDS16(w0 + 32768,  bd0 + 4096);
    GL_LDS16(w0 + 34816,  bd0 + 6144);
    const int ko = it * 64;
#define ASTAGE(XS, AW) { f32x4 u = *(const f32x4*)((XS) + ko); f32x4 v = *(const f32x4*)((XS) + ko + 4); \
    u16x8 h;                                                                              \
    h[0] = cvtbf(u[0]); h[1] = cvtbf(u[1]); h[2] = cvtbf(u[2]); h[3] = cvtbf(u[3]);       \
    h[4] = cvtbf(v[0]); h[5] = cvtbf(v[1]); h[6] = cvtbf(v[2]); h[7] = cvtbf(v[3]);       \
    *(u16x8*)((char*)As + (AW)) = h; }
    ASTAGE(xs0, aw0) ASTAGE(xs1, aw1) ASTAGE(xs2, aw2) ASTAGE(xs3, aw3)
#undef ASTAGE
    __syncthreads();
#pragma unroll
    for (int kt2 = 0; kt2 < 2; ++kt2) {
      s16x8 af[4], bfr[4];
#pragma unroll
      for (int m = 0; m < 4; ++m) af[m] = *(const s16x8*)(Ab + ((kt2 * 8 + wr * 4 + m) << 10));
#pragma unroll
      for (int n = 0; n < 4; ++n) bfr[n] = *(const s16x8*)(Bb + ((kt2 * 8 + wc * 4 + n) << 10));
#pragma unroll
      for (int m = 0; m < 4; ++m)
#pragma unroll
        for (int n = 0; n < 4; ++n)
          acc[m][n] = __builtin_amdgcn_mfma_f32_16x16x32_bf16(af[m], bfr[n], acc[m][n], 0, 0, 0);
    }
    __syncthreads();
  }

  const long orow0 = m0 + wr * 64 + (lane >> 4) * 4;
  const int  ocol0 = n0 + wc * 64 + (lane & 15);
#pragma unroll
  for (int n = 0; n < 4; ++n) {
    const int cc = ocol0 + n * 16;
    const float bb = bvec[cc];
#pragma unroll
    for (int m = 0; m < 4; ++m) {
      const long r = orow0 + m * 16;
#pragma unroll
      for (int q = 0; q < 4; ++q)
        out[(r + q) * 1024 + cc] = acc[m][n][q] + bb;
    }
  }
}

extern "C" void kernel_launch(void* const* d_in, const int* in_sizes, int n_in,
                              void* d_out, int out_size, void* d_ws, size_t ws_size,
                              hipStream_t stream) {
  const float* x  = (const float*)d_in[0];
  const float* A  = (const float*)d_in[1];
  const float* bv = (const float*)d_in[2];
  float* out = (float*)d_out;
  char* ws = (char*)d_ws;

  float* B   = (float*)(ws);                              // 4 MB, becomes Y
  float* Y   = B;
  float* M   = (float*)(ws + (4u << 20));                 // 4 MB
  u16*   Wf  = (u16*)  (ws + (8u << 20));                 // 2 MB
  float* rd2 = (float*)(ws + (10u << 20));                // 4 KB
  float* U   = (float*)(ws + (10u << 20) + 65536);        // 1 MB
  u16*   Xbf = (u16*)  (ws + (12u << 20));                // 128 MB

  const size_t need = (12u << 20) + (size_t)65536 * 1024 * 2;
  const bool big = (ws_size >= need);

  k_bbtx<<<big ? 1160 : 136, 256, 0, stream>>>(A, B, rd2, M, x, Xbf);
  k_lvl0<<<8, 256, 0, stream>>>(B, rd2, M);
  for (int lvl = 1; lvl < 4; ++lvl) {
    const int nt2 = 1 << (2 * lvl);
    const int np  = 8 >> lvl;
    k_u<<<dim3(nt2, np), 256, 0, stream>>>(B, rd2, M, U, lvl);
    k_moff<<<dim3(nt2, np), 256, 0, stream>>>(M, U, lvl);
  }
  k_yma<<<big ? 768 : 256, 256, 0, stream>>>(M, A, Y, x, Xbf);
  k_w<<<big ? 768 : 256, 256, 0, stream>>>(A, Y, rd2, Wf, x, Xbf);

  if (big) {
    k_out8<<<1024, 1024, 0, stream>>>(Xbf, Wf, bv, out);
  } else {
    k_out_r<<<4096, 256, 0, stream>>>(x, Wf, bv, out);
  }
}